// Round 4
// baseline (282.829 us; speedup 1.0000x reference)
//
#include <hip/hip_runtime.h>
#include <math.h>

// AVWGCN: B=64, N=2048, C_IN=C_OUT=64, CHEB_K=3, EMBED=16
#define NN    2048
#define BATCH 64
#define CIN   64
#define COUT  64
#define EMB   16
#define JDIM  4096   // BATCH*CIN
#define WKI   192    // CHEB_K*CIN

typedef __bf16 bf16_t;
typedef __bf16 bf16x8 __attribute__((ext_vector_type(8)));
typedef float  f32x4  __attribute__((ext_vector_type(4)));

#define GLOAD16(gp, lp) __builtin_amdgcn_global_load_lds( \
    (const __attribute__((address_space(1))) void*)(gp),  \
    (__attribute__((address_space(3))) void*)(lp), 16, 0, 0)

static __device__ __forceinline__ unsigned short bfbits(float f) {
    return __builtin_bit_cast(unsigned short, (bf16_t)f);
}

// ---------------------------------------------------------------------------
// Wt[n][o][ki] = sum_d E[n,d] * wp[d][k][i][o], bf16.  oki = o*192 + k*64 + i.
// Grid (24, 64): 512-wide oki slice (2/thread in regs), 32-node inner loop.
// 1536 blocks -> ~6 blocks/CU for latency hiding of the dependent FMA chains.
// ---------------------------------------------------------------------------
__global__ __launch_bounds__(256) void wgen_kernel(
    const float* __restrict__ E, const float* __restrict__ wp,
    bf16_t* __restrict__ Wt) {
    const int R  = blockIdx.x * 512;
    const int n0 = blockIdx.y * 32;
    const int t  = threadIdx.x;
    const int oki0 = R + 2 * t;
    float w0[EMB], w1[EMB];
    {
        const int o0 = oki0 / WKI, r0 = oki0 % WKI;
        const int o1 = (oki0 + 1) / WKI, r1 = (oki0 + 1) % WKI;
#pragma unroll
        for (int d = 0; d < EMB; ++d) {
            w0[d] = wp[(size_t)(d * WKI + r0) * 64 + o0];
            w1[d] = wp[(size_t)(d * WKI + r1) * 64 + o1];
        }
    }
#pragma unroll 4
    for (int nn = 0; nn < 32; ++nn) {
        const int n = n0 + nn;
        const float4* e4 = reinterpret_cast<const float4*>(E + (size_t)n * EMB);
        float a0 = 0.f, a1 = 0.f;
#pragma unroll
        for (int q = 0; q < 4; ++q) {
            float4 ev = e4[q];
            a0 += ev.x*w0[q*4+0] + ev.y*w0[q*4+1] + ev.z*w0[q*4+2] + ev.w*w0[q*4+3];
            a1 += ev.x*w1[q*4+0] + ev.y*w1[q*4+1] + ev.z*w1[q*4+2] + ev.w*w1[q*4+3];
        }
        unsigned int pk = (unsigned int)bfbits(a0) | ((unsigned int)bfbits(a1) << 16);
        *reinterpret_cast<unsigned int*>(Wt + (size_t)n * 12288 + oki0) = pk;
    }
}

// ---------------------------------------------------------------------------
// x (B,N,C) fp32 -> Y0 (JDIM, NN) bf16 : Y0[b*64+c][n] = x[b][n][c]
// ---------------------------------------------------------------------------
__global__ __launch_bounds__(256) void y0_kernel(const float* __restrict__ x,
                                                 bf16_t* __restrict__ Y0) {
    __shared__ float tile[64][65];
    const int n0 = blockIdx.x * 64, b = blockIdx.y, tid = threadIdx.x;
    const int c = tid & 63, nn0 = tid >> 6;
    const float* src = x + ((size_t)b * NN + n0) * CIN + c;
#pragma unroll
    for (int p = 0; p < 16; ++p) {
        int nn = nn0 + p * 4;
        tile[nn][c] = src[(size_t)nn * CIN];
    }
    __syncthreads();
    const int cc = tid >> 2, q = tid & 3;
    bf16_t* dst = Y0 + (size_t)(b * 64 + cc) * NN + n0 + q * 16;
#pragma unroll
    for (int s4 = 0; s4 < 4; ++s4) {
        ushort4 pk;
        pk.x = bfbits(tile[q * 16 + s4 * 4 + 0][cc]);
        pk.y = bfbits(tile[q * 16 + s4 * 4 + 1][cc]);
        pk.z = bfbits(tile[q * 16 + s4 * 4 + 2][cc]);
        pk.w = bfbits(tile[q * 16 + s4 * 4 + 3][cc]);
        *reinterpret_cast<ushort4*>(dst + s4 * 4) = pk;
    }
}

// ---------------------------------------------------------------------------
// Sb[n,:] = softmax(relu(E[n] @ E^T)) as bf16, one block per row
// ---------------------------------------------------------------------------
__global__ __launch_bounds__(256) void support_kernel(
    const float* __restrict__ E, bf16_t* __restrict__ Sb) {
    const int n = blockIdx.x, tid = threadIdx.x;
    __shared__ float vals[NN];
    __shared__ float red[4];

    float en[EMB];
#pragma unroll
    for (int d = 0; d < EMB; ++d) en[d] = E[n * EMB + d];

    float lmax = -1e30f;
    for (int m = tid; m < NN; m += 256) {
        const float4* em = reinterpret_cast<const float4*>(E + m * EMB);
        float dot = 0.f;
#pragma unroll
        for (int q = 0; q < EMB / 4; ++q) {
            float4 v = em[q];
            dot += en[q*4+0]*v.x + en[q*4+1]*v.y + en[q*4+2]*v.z + en[q*4+3]*v.w;
        }
        float r = fmaxf(dot, 0.f);
        vals[m] = r;
        lmax = fmaxf(lmax, r);
    }
#pragma unroll
    for (int off = 32; off > 0; off >>= 1)
        lmax = fmaxf(lmax, __shfl_down(lmax, off, 64));
    if ((tid & 63) == 0) red[tid >> 6] = lmax;
    __syncthreads();
    const float gmax = fmaxf(fmaxf(red[0], red[1]), fmaxf(red[2], red[3]));
    __syncthreads();

    float lsum = 0.f;
    for (int m = tid; m < NN; m += 256) {
        float e = expf(vals[m] - gmax);
        vals[m] = e;
        lsum += e;
    }
#pragma unroll
    for (int off = 32; off > 0; off >>= 1)
        lsum += __shfl_down(lsum, off, 64);
    if ((tid & 63) == 0) red[tid >> 6] = lsum;
    __syncthreads();
    const float inv = 1.f / (red[0] + red[1] + red[2] + red[3]);

    for (int m = tid; m < NN; m += 256)
        Sb[(size_t)n * NN + m] = (bf16_t)(vals[m] * inv);
}

// ---------------------------------------------------------------------------
// C(4096x2048) = A @ Bt^T (both K=node contiguous, bf16).
// MODE 0: writes Cj (j-major, scale 1) AND GT (node-major, scale 1)
// MODE 1: writes only GT (node-major, scale 2)
// ---------------------------------------------------------------------------
template<int MODE>
__global__ __launch_bounds__(256) void gemm_bt(
    const bf16_t* __restrict__ A, const bf16_t* __restrict__ Bt,
    bf16_t* __restrict__ Cj, bf16_t* __restrict__ GT) {
    __shared__ bf16_t smem[128 * 136];    // 34.8 KB; union of {As,Bs} and T
    bf16_t* As = smem;                    // 128*32
    bf16_t* Bs = smem + 4096;             // 128*32
    bf16_t* T  = smem;                    // 128*136 (epilogue reuse)
    const int tid  = threadIdx.x;
    const int wave = tid >> 6, lane = tid & 63;
    const int pBlk = blockIdx.x * 128;    // node cols
    const int mBlk = blockIdx.y * 128;    // j rows
    const int K = NN;

    const bf16_t* aSrc = A  + (size_t)(mBlk + wave * 32 + (lane >> 2)) * K + (lane & 3) * 8;
    const bf16_t* bSrc = Bt + (size_t)(pBlk + wave * 32 + (lane >> 2)) * K + (lane & 3) * 8;
    bf16_t* aDst = As + wave * 1024;
    bf16_t* bDst = Bs + wave * 1024;

    f32x4 acc[4][4] = {};
    const int wr = wave >> 1, wc = wave & 1;
    const int lrow = lane & 15, lk = (lane >> 4) * 8;

    for (int k0 = 0; k0 < K; k0 += 32) {
        GLOAD16(aSrc + k0,                  aDst);
        GLOAD16(aSrc + k0 + (size_t)16 * K, aDst + 512);
        GLOAD16(bSrc + k0,                  bDst);
        GLOAD16(bSrc + k0 + (size_t)16 * K, bDst + 512);
        __syncthreads();

        bf16x8 af[4], bb[4];
#pragma unroll
        for (int mf = 0; mf < 4; ++mf)
            af[mf] = *reinterpret_cast<const bf16x8*>(
                &As[(wr * 64 + mf * 16 + lrow) * 32 + lk]);
#pragma unroll
        for (int nf = 0; nf < 4; ++nf)
            bb[nf] = *reinterpret_cast<const bf16x8*>(
                &Bs[(wc * 64 + nf * 16 + lrow) * 32 + lk]);
#pragma unroll
        for (int mf = 0; mf < 4; ++mf)
#pragma unroll
            for (int nf = 0; nf < 4; ++nf)
                acc[mf][nf] = __builtin_amdgcn_mfma_f32_16x16x32_bf16(
                    af[mf], bb[nf], acc[mf][nf], 0, 0, 0);
        __syncthreads();
    }

    // epilogue. C/D layout: col = lane&15, row = (lane>>4)*4 + r  [m89]
    const int orow = (lane >> 4) * 4, ocol = lane & 15;
    if (MODE == 0) {
#pragma unroll
        for (int mf = 0; mf < 4; ++mf)
#pragma unroll
            for (int nf = 0; nf < 4; ++nf)
#pragma unroll
                for (int r = 0; r < 4; ++r) {
                    size_t row = (size_t)(mBlk + wr * 64 + mf * 16 + orow + r);
                    size_t col = (size_t)(pBlk + wc * 64 + nf * 16 + ocol);
                    Cj[row * NN + col] = (bf16_t)acc[mf][nf][r];
                }
    }
    const float scale = (MODE == 1) ? 2.f : 1.f;
#pragma unroll
    for (int mf = 0; mf < 4; ++mf)
#pragma unroll
        for (int nf = 0; nf < 4; ++nf)
#pragma unroll
            for (int r = 0; r < 4; ++r) {
                int trow = wr * 64 + mf * 16 + orow + r;   // local j
                int tcol = wc * 64 + nf * 16 + ocol;       // local n
                T[(size_t)tcol * 136 + trow] = (bf16_t)(scale * acc[mf][nf][r]);
            }
    __syncthreads();
    {
        const int row = tid >> 1, half = tid & 1;          // local n, j-half
        const bf16_t* src = T + (size_t)row * 136 + half * 64;
        bf16_t* dst = GT + (size_t)(pBlk + row) * JDIM + mBlk + half * 64;
#pragma unroll
        for (int s = 0; s < 8; ++s)
            *reinterpret_cast<uint4*>(dst + s * 8) =
                *reinterpret_cast<const uint4*>(src + s * 8);
    }
}

// ---------------------------------------------------------------------------
// Final grouped matmul, MFMA. One node per block (grid NN) for occupancy.
// Wt B-fragments + bias dot hoisted ABOVE the barrier so their global-load
// latency hides under the stage drain.
// ---------------------------------------------------------------------------
__global__ __launch_bounds__(256) void gconv_kernel(
    const float* __restrict__ x,   const float* __restrict__ E,
    const float* __restrict__ bp,  const bf16_t* __restrict__ G1T,
    const bf16_t* __restrict__ G2T, const bf16_t* __restrict__ Wt,
    float* __restrict__ out) {
    __shared__ bf16_t g[64][200];          // 25.6 KB
    const int n = blockIdx.x;
    const int tid = threadIdx.x, wave = tid >> 6, lane = tid & 63;
    const int lrow = lane & 15, lk = (lane >> 4) * 8;
    const int o = wave * 16 + lrow;        // this lane's output col

    // ---- prefetch Wt fragments + bias (independent of LDS) ----
    const bf16_t* wtn = Wt + (size_t)n * 12288 + (size_t)o * WKI;
    bf16x8 bb[6];
#pragma unroll
    for (int ks = 0; ks < 6; ++ks)
        bb[ks] = *reinterpret_cast<const bf16x8*>(wtn + ks * 32 + lk);
    float bo = 0.f;
    {
        const float* en = E + (size_t)n * EMB;
#pragma unroll
        for (int d = 0; d < EMB; ++d) bo += en[d] * bp[d * COUT + o];
    }

    // ---- stage g (cooperative) ----
#pragma unroll
    for (int p = 0; p < 2; ++p) {
        int idx = p * 256 + tid;                 // 0..511
        int b = idx >> 3, ic = (idx & 7) * 8;
        const float4* xs = reinterpret_cast<const float4*>(
            x + ((size_t)b * NN + n) * CIN + ic);
        float4 x0 = xs[0], x1 = xs[1];
        uint4 g1v = *reinterpret_cast<const uint4*>(G1T + (size_t)n * JDIM + idx * 8);
        uint4 g2v = *reinterpret_cast<const uint4*>(G2T + (size_t)n * JDIM + idx * 8);
        float xv[8] = {x0.x, x0.y, x0.z, x0.w, x1.x, x1.y, x1.z, x1.w};
        const bf16_t* g2p = reinterpret_cast<const bf16_t*>(&g2v);
        ushort4 g0b[2], g2b[2];
#pragma unroll
        for (int e = 0; e < 8; ++e) {
            ((unsigned short*)g0b)[e] = bfbits(xv[e]);
            ((unsigned short*)g2b)[e] = bfbits((float)g2p[e] - xv[e]);
        }
        *reinterpret_cast<uint4*>(&g[b][ic])       = *reinterpret_cast<uint4*>(g0b);
        *reinterpret_cast<uint4*>(&g[b][64 + ic])  = g1v;
        *reinterpret_cast<uint4*>(&g[b][128 + ic]) = *reinterpret_cast<uint4*>(g2b);
    }
    __syncthreads();

    // ---- compute: 64x16 output slice per wave, K=192 ----
    f32x4 acc[4] = {};
#pragma unroll
    for (int ks = 0; ks < 6; ++ks)
#pragma unroll
        for (int mf = 0; mf < 4; ++mf) {
            bf16x8 af = *reinterpret_cast<const bf16x8*>(&g[mf * 16 + lrow][ks * 32 + lk]);
            acc[mf] = __builtin_amdgcn_mfma_f32_16x16x32_bf16(af, bb[ks], acc[mf], 0, 0, 0);
        }
#pragma unroll
    for (int mf = 0; mf < 4; ++mf)
#pragma unroll
        for (int r = 0; r < 4; ++r) {
            int b = mf * 16 + (lane >> 4) * 4 + r;
            out[((size_t)b * NN + n) * COUT + o] = acc[mf][r] + bo;
        }
}

// ---------------------------------------------------------------------------
extern "C" void kernel_launch(void* const* d_in, const int* in_sizes, int n_in,
                              void* d_out, int out_size, void* d_ws, size_t ws_size,
                              hipStream_t stream) {
    const float* x  = (const float*)d_in[0];   // (64,2048,64)
    const float* E  = (const float*)d_in[1];   // (2048,16)
    const float* wp = (const float*)d_in[2];   // (16,3,64,64)
    const float* bp = (const float*)d_in[3];   // (16,64)
    float* out = (float*)d_out;

    bf16_t* ws = (bf16_t*)d_ws;
    bf16_t* Wt  = ws;                          // 2048*12288      = 48 MB
    bf16_t* Sb  = Wt + (size_t)NN * 12288;     // 2048*2048       =  8 MB
    bf16_t* Y0  = Sb + (size_t)NN * NN;        // 4096*2048       = 16 MB
    bf16_t* Y1  = Y0 + (size_t)JDIM * NN;      // 16 MB
    bf16_t* G1T = Y1 + (size_t)JDIM * NN;      // 16 MB  (total 104 MB)
    bf16_t* G2T = Y0;                          // alias: Y0 dead after gemm<0>

    wgen_kernel<<<dim3(12288 / 512, NN / 32), 256, 0, stream>>>(E, wp, Wt);
    support_kernel<<<NN, 256, 0, stream>>>(E, Sb);
    y0_kernel<<<dim3(NN / 64, BATCH), 256, 0, stream>>>(x, Y0);

    dim3 ggrid(NN / 128, JDIM / 128);          // 16 x 32 = 512 blocks
    gemm_bt<0><<<ggrid, 256, 0, stream>>>(Y0, Sb, Y1, G1T);
    gemm_bt<1><<<ggrid, 256, 0, stream>>>(Y1, Sb, nullptr, G2T);

    gconv_kernel<<<NN, 256, 0, stream>>>(x, E, bp, G1T, G2T, Wt, out);
}

// Round 5
// 279.711 us; speedup vs baseline: 1.0111x; 1.0111x over previous
//
#include <hip/hip_runtime.h>
#include <math.h>

// AVWGCN: B=64, N=2048, C_IN=C_OUT=64, CHEB_K=3, EMBED=16
#define NN    2048
#define BATCH 64
#define CIN   64
#define COUT  64
#define EMB   16
#define JDIM  4096   // BATCH*CIN
#define WKI   192    // CHEB_K*CIN

typedef __bf16 bf16_t;
typedef __bf16 bf16x8 __attribute__((ext_vector_type(8)));
typedef float  f32x4  __attribute__((ext_vector_type(4)));

#define GLOAD16(gp, lp) __builtin_amdgcn_global_load_lds( \
    (const __attribute__((address_space(1))) void*)(gp),  \
    (__attribute__((address_space(3))) void*)(lp), 16, 0, 0)

static __device__ __forceinline__ unsigned short bfbits(float f) {
    return __builtin_bit_cast(unsigned short, (bf16_t)f);
}

// ---------------------------------------------------------------------------
// Wt[n][o][ki] = sum_d E[n,d] * wp[d][k][i][o], bf16.  oki = o*192 + ki.
// v3: E chunk staged in LDS (broadcast ds_reads), 4 outputs/thread (one o,
// r0..r0+3), 8B stores. Grid (12, 64) = 768 blocks, 32-node inner loop.
// ---------------------------------------------------------------------------
__global__ __launch_bounds__(256) void wgen_kernel(
    const float* __restrict__ E, const float* __restrict__ wp,
    bf16_t* __restrict__ Wt) {
    __shared__ float sE[32][16];           // 2 KB
    const int n0 = blockIdx.y * 32;
    const int t  = threadIdx.x;
    const int oki0 = blockIdx.x * 1024 + 4 * t;
    const int o  = oki0 / WKI, r0 = oki0 % WKI;   // r0 % 4 == 0, r0 <= 188

    // stage E[n0:n0+32] (512 floats) cooperatively
    if (t < 128) {
        const int node = t >> 2, q = t & 3;
        *reinterpret_cast<float4*>(&sE[node][q * 4]) =
            *reinterpret_cast<const float4*>(E + (size_t)(n0 + node) * EMB + q * 4);
    }

    // per-thread wp slice: w[j][d], j = 4 consecutive r at fixed o
    float w[4][EMB];
#pragma unroll
    for (int d = 0; d < EMB; ++d)
#pragma unroll
        for (int j = 0; j < 4; ++j)
            w[j][d] = wp[(size_t)(d * WKI + r0 + j) * 64 + o];

    __syncthreads();

#pragma unroll 2
    for (int nn = 0; nn < 32; ++nn) {
        float4 e0 = *reinterpret_cast<const float4*>(&sE[nn][0]);
        float4 e1 = *reinterpret_cast<const float4*>(&sE[nn][4]);
        float4 e2 = *reinterpret_cast<const float4*>(&sE[nn][8]);
        float4 e3 = *reinterpret_cast<const float4*>(&sE[nn][12]);
        float en[EMB] = {e0.x,e0.y,e0.z,e0.w, e1.x,e1.y,e1.z,e1.w,
                         e2.x,e2.y,e2.z,e2.w, e3.x,e3.y,e3.z,e3.w};
        float a[4] = {};
#pragma unroll
        for (int d = 0; d < EMB; ++d) {
#pragma unroll
            for (int j = 0; j < 4; ++j) a[j] += en[d] * w[j][d];
        }
        ushort4 pk;
        pk.x = bfbits(a[0]); pk.y = bfbits(a[1]);
        pk.z = bfbits(a[2]); pk.w = bfbits(a[3]);
        *reinterpret_cast<ushort4*>(Wt + (size_t)(n0 + nn) * 12288 + oki0) = pk;
    }
}

// ---------------------------------------------------------------------------
// x (B,N,C) fp32 -> Y0 (JDIM, NN) bf16 : Y0[b*64+c][n] = x[b][n][c]
// ---------------------------------------------------------------------------
__global__ __launch_bounds__(256) void y0_kernel(const float* __restrict__ x,
                                                 bf16_t* __restrict__ Y0) {
    __shared__ float tile[64][65];
    const int n0 = blockIdx.x * 64, b = blockIdx.y, tid = threadIdx.x;
    const int c = tid & 63, nn0 = tid >> 6;
    const float* src = x + ((size_t)b * NN + n0) * CIN + c;
#pragma unroll
    for (int p = 0; p < 16; ++p) {
        int nn = nn0 + p * 4;
        tile[nn][c] = src[(size_t)nn * CIN];
    }
    __syncthreads();
    const int cc = tid >> 2, q = tid & 3;
    bf16_t* dst = Y0 + (size_t)(b * 64 + cc) * NN + n0 + q * 16;
#pragma unroll
    for (int s4 = 0; s4 < 4; ++s4) {
        ushort4 pk;
        pk.x = bfbits(tile[q * 16 + s4 * 4 + 0][cc]);
        pk.y = bfbits(tile[q * 16 + s4 * 4 + 1][cc]);
        pk.z = bfbits(tile[q * 16 + s4 * 4 + 2][cc]);
        pk.w = bfbits(tile[q * 16 + s4 * 4 + 3][cc]);
        *reinterpret_cast<ushort4*>(dst + s4 * 4) = pk;
    }
}

// ---------------------------------------------------------------------------
// Sb[n,:] = softmax(relu(E[n] @ E^T)) as bf16, one block per row
// ---------------------------------------------------------------------------
__global__ __launch_bounds__(256) void support_kernel(
    const float* __restrict__ E, bf16_t* __restrict__ Sb) {
    const int n = blockIdx.x, tid = threadIdx.x;
    __shared__ float vals[NN];
    __shared__ float red[4];

    float en[EMB];
#pragma unroll
    for (int d = 0; d < EMB; ++d) en[d] = E[n * EMB + d];

    float lmax = -1e30f;
    for (int m = tid; m < NN; m += 256) {
        const float4* em = reinterpret_cast<const float4*>(E + m * EMB);
        float dot = 0.f;
#pragma unroll
        for (int q = 0; q < EMB / 4; ++q) {
            float4 v = em[q];
            dot += en[q*4+0]*v.x + en[q*4+1]*v.y + en[q*4+2]*v.z + en[q*4+3]*v.w;
        }
        float r = fmaxf(dot, 0.f);
        vals[m] = r;
        lmax = fmaxf(lmax, r);
    }
#pragma unroll
    for (int off = 32; off > 0; off >>= 1)
        lmax = fmaxf(lmax, __shfl_down(lmax, off, 64));
    if ((tid & 63) == 0) red[tid >> 6] = lmax;
    __syncthreads();
    const float gmax = fmaxf(fmaxf(red[0], red[1]), fmaxf(red[2], red[3]));
    __syncthreads();

    float lsum = 0.f;
    for (int m = tid; m < NN; m += 256) {
        float e = expf(vals[m] - gmax);
        vals[m] = e;
        lsum += e;
    }
#pragma unroll
    for (int off = 32; off > 0; off >>= 1)
        lsum += __shfl_down(lsum, off, 64);
    if ((tid & 63) == 0) red[tid >> 6] = lsum;
    __syncthreads();
    const float inv = 1.f / (red[0] + red[1] + red[2] + red[3]);

    for (int m = tid; m < NN; m += 256)
        Sb[(size_t)n * NN + m] = (bf16_t)(vals[m] * inv);
}

// ---------------------------------------------------------------------------
// C(4096x2048) = A @ Bt^T (both K=node contiguous, bf16).
// MODE 0: writes Cj (j-major, scale 1) AND GT (node-major, scale 1)
// MODE 1: writes only GT (node-major, scale 2)
// ---------------------------------------------------------------------------
template<int MODE>
__global__ __launch_bounds__(256) void gemm_bt(
    const bf16_t* __restrict__ A, const bf16_t* __restrict__ Bt,
    bf16_t* __restrict__ Cj, bf16_t* __restrict__ GT) {
    __shared__ bf16_t smem[128 * 136];    // 34.8 KB; union of {As,Bs} and T
    bf16_t* As = smem;                    // 128*32
    bf16_t* Bs = smem + 4096;             // 128*32
    bf16_t* T  = smem;                    // 128*136 (epilogue reuse)
    const int tid  = threadIdx.x;
    const int wave = tid >> 6, lane = tid & 63;
    const int pBlk = blockIdx.x * 128;    // node cols
    const int mBlk = blockIdx.y * 128;    // j rows
    const int K = NN;

    const bf16_t* aSrc = A  + (size_t)(mBlk + wave * 32 + (lane >> 2)) * K + (lane & 3) * 8;
    const bf16_t* bSrc = Bt + (size_t)(pBlk + wave * 32 + (lane >> 2)) * K + (lane & 3) * 8;
    bf16_t* aDst = As + wave * 1024;
    bf16_t* bDst = Bs + wave * 1024;

    f32x4 acc[4][4] = {};
    const int wr = wave >> 1, wc = wave & 1;
    const int lrow = lane & 15, lk = (lane >> 4) * 8;

    for (int k0 = 0; k0 < K; k0 += 32) {
        GLOAD16(aSrc + k0,                  aDst);
        GLOAD16(aSrc + k0 + (size_t)16 * K, aDst + 512);
        GLOAD16(bSrc + k0,                  bDst);
        GLOAD16(bSrc + k0 + (size_t)16 * K, bDst + 512);
        __syncthreads();

        bf16x8 af[4], bb[4];
#pragma unroll
        for (int mf = 0; mf < 4; ++mf)
            af[mf] = *reinterpret_cast<const bf16x8*>(
                &As[(wr * 64 + mf * 16 + lrow) * 32 + lk]);
#pragma unroll
        for (int nf = 0; nf < 4; ++nf)
            bb[nf] = *reinterpret_cast<const bf16x8*>(
                &Bs[(wc * 64 + nf * 16 + lrow) * 32 + lk]);
#pragma unroll
        for (int mf = 0; mf < 4; ++mf)
#pragma unroll
            for (int nf = 0; nf < 4; ++nf)
                acc[mf][nf] = __builtin_amdgcn_mfma_f32_16x16x32_bf16(
                    af[mf], bb[nf], acc[mf][nf], 0, 0, 0);
        __syncthreads();
    }

    // epilogue. C/D layout: col = lane&15, row = (lane>>4)*4 + r  [m89]
    const int orow = (lane >> 4) * 4, ocol = lane & 15;
    if (MODE == 0) {
#pragma unroll
        for (int mf = 0; mf < 4; ++mf)
#pragma unroll
            for (int nf = 0; nf < 4; ++nf)
#pragma unroll
                for (int r = 0; r < 4; ++r) {
                    size_t row = (size_t)(mBlk + wr * 64 + mf * 16 + orow + r);
                    size_t col = (size_t)(pBlk + wc * 64 + nf * 16 + ocol);
                    Cj[row * NN + col] = (bf16_t)acc[mf][nf][r];
                }
    }
    const float scale = (MODE == 1) ? 2.f : 1.f;
#pragma unroll
    for (int mf = 0; mf < 4; ++mf)
#pragma unroll
        for (int nf = 0; nf < 4; ++nf)
#pragma unroll
            for (int r = 0; r < 4; ++r) {
                int trow = wr * 64 + mf * 16 + orow + r;   // local j
                int tcol = wc * 64 + nf * 16 + ocol;       // local n
                T[(size_t)tcol * 136 + trow] = (bf16_t)(scale * acc[mf][nf][r]);
            }
    __syncthreads();
    {
        const int row = tid >> 1, half = tid & 1;          // local n, j-half
        const bf16_t* src = T + (size_t)row * 136 + half * 64;
        bf16_t* dst = GT + (size_t)(pBlk + row) * JDIM + mBlk + half * 64;
#pragma unroll
        for (int s = 0; s < 8; ++s)
            *reinterpret_cast<uint4*>(dst + s * 8) =
                *reinterpret_cast<const uint4*>(src + s * 8);
    }
}

// ---------------------------------------------------------------------------
// Final grouped matmul, MFMA. One node per block (grid NN).
// Wt B-fragments + bias dot hoisted above the barrier.
// ---------------------------------------------------------------------------
__global__ __launch_bounds__(256) void gconv_kernel(
    const float* __restrict__ x,   const float* __restrict__ E,
    const float* __restrict__ bp,  const bf16_t* __restrict__ G1T,
    const bf16_t* __restrict__ G2T, const bf16_t* __restrict__ Wt,
    float* __restrict__ out) {
    __shared__ bf16_t g[64][200];          // 25.6 KB
    const int n = blockIdx.x;
    const int tid = threadIdx.x, wave = tid >> 6, lane = tid & 63;
    const int lrow = lane & 15, lk = (lane >> 4) * 8;
    const int o = wave * 16 + lrow;        // this lane's output col

    // ---- prefetch Wt fragments + bias (independent of LDS) ----
    const bf16_t* wtn = Wt + (size_t)n * 12288 + (size_t)o * WKI;
    bf16x8 bb[6];
#pragma unroll
    for (int ks = 0; ks < 6; ++ks)
        bb[ks] = *reinterpret_cast<const bf16x8*>(wtn + ks * 32 + lk);
    float bo = 0.f;
    {
        const float* en = E + (size_t)n * EMB;
#pragma unroll
        for (int d = 0; d < EMB; ++d) bo += en[d] * bp[d * COUT + o];
    }

    // ---- stage g (cooperative) ----
#pragma unroll
    for (int p = 0; p < 2; ++p) {
        int idx = p * 256 + tid;                 // 0..511
        int b = idx >> 3, ic = (idx & 7) * 8;
        const float4* xs = reinterpret_cast<const float4*>(
            x + ((size_t)b * NN + n) * CIN + ic);
        float4 x0 = xs[0], x1 = xs[1];
        uint4 g1v = *reinterpret_cast<const uint4*>(G1T + (size_t)n * JDIM + idx * 8);
        uint4 g2v = *reinterpret_cast<const uint4*>(G2T + (size_t)n * JDIM + idx * 8);
        float xv[8] = {x0.x, x0.y, x0.z, x0.w, x1.x, x1.y, x1.z, x1.w};
        const bf16_t* g2p = reinterpret_cast<const bf16_t*>(&g2v);
        ushort4 g0b[2], g2b[2];
#pragma unroll
        for (int e = 0; e < 8; ++e) {
            ((unsigned short*)g0b)[e] = bfbits(xv[e]);
            ((unsigned short*)g2b)[e] = bfbits((float)g2p[e] - xv[e]);
        }
        *reinterpret_cast<uint4*>(&g[b][ic])       = *reinterpret_cast<uint4*>(g0b);
        *reinterpret_cast<uint4*>(&g[b][64 + ic])  = g1v;
        *reinterpret_cast<uint4*>(&g[b][128 + ic]) = *reinterpret_cast<uint4*>(g2b);
    }
    __syncthreads();

    // ---- compute: 64x16 output slice per wave, K=192 ----
    f32x4 acc[4] = {};
#pragma unroll
    for (int ks = 0; ks < 6; ++ks)
#pragma unroll
        for (int mf = 0; mf < 4; ++mf) {
            bf16x8 af = *reinterpret_cast<const bf16x8*>(&g[mf * 16 + lrow][ks * 32 + lk]);
            acc[mf] = __builtin_amdgcn_mfma_f32_16x16x32_bf16(af, bb[ks], acc[mf], 0, 0, 0);
        }
#pragma unroll
    for (int mf = 0; mf < 4; ++mf)
#pragma unroll
        for (int r = 0; r < 4; ++r) {
            int b = mf * 16 + (lane >> 4) * 4 + r;
            out[((size_t)b * NN + n) * COUT + o] = acc[mf][r] + bo;
        }
}

// ---------------------------------------------------------------------------
extern "C" void kernel_launch(void* const* d_in, const int* in_sizes, int n_in,
                              void* d_out, int out_size, void* d_ws, size_t ws_size,
                              hipStream_t stream) {
    const float* x  = (const float*)d_in[0];   // (64,2048,64)
    const float* E  = (const float*)d_in[1];   // (2048,16)
    const float* wp = (const float*)d_in[2];   // (16,3,64,64)
    const float* bp = (const float*)d_in[3];   // (16,64)
    float* out = (float*)d_out;

    bf16_t* ws = (bf16_t*)d_ws;
    bf16_t* Wt  = ws;                          // 2048*12288      = 48 MB
    bf16_t* Sb  = Wt + (size_t)NN * 12288;     // 2048*2048       =  8 MB
    bf16_t* Y0  = Sb + (size_t)NN * NN;        // 4096*2048       = 16 MB
    bf16_t* Y1  = Y0 + (size_t)JDIM * NN;      // 16 MB
    bf16_t* G1T = Y1 + (size_t)JDIM * NN;      // 16 MB  (total 104 MB)
    bf16_t* G2T = Y0;                          // alias: Y0 dead after gemm<0>

    wgen_kernel<<<dim3(12288 / 1024, NN / 32), 256, 0, stream>>>(E, wp, Wt);
    support_kernel<<<NN, 256, 0, stream>>>(E, Sb);
    y0_kernel<<<dim3(NN / 64, BATCH), 256, 0, stream>>>(x, Y0);

    dim3 ggrid(NN / 128, JDIM / 128);          // 16 x 32 = 512 blocks
    gemm_bt<0><<<ggrid, 256, 0, stream>>>(Y0, Sb, Y1, G1T);
    gemm_bt<1><<<ggrid, 256, 0, stream>>>(Y1, Sb, nullptr, G2T);

    gconv_kernel<<<NN, 256, 0, stream>>>(x, E, bp, G1T, G2T, Wt, out);
}

// Round 6
// 264.123 us; speedup vs baseline: 1.0708x; 1.0590x over previous
//
#include <hip/hip_runtime.h>
#include <math.h>

// AVWGCN: B=64, N=2048, C_IN=C_OUT=64, CHEB_K=3, EMBED=16
#define NN    2048
#define BATCH 64
#define CIN   64
#define COUT  64
#define EMB   16
#define JDIM  4096   // BATCH*CIN
#define WKI   192    // CHEB_K*CIN

typedef __bf16 bf16_t;
typedef __bf16 bf16x8 __attribute__((ext_vector_type(8)));
typedef float  f32x4  __attribute__((ext_vector_type(4)));
typedef unsigned int u32x2 __attribute__((ext_vector_type(2)));
typedef unsigned int u32x4 __attribute__((ext_vector_type(4)));

#define GLOAD16(gp, lp) __builtin_amdgcn_global_load_lds( \
    (const __attribute__((address_space(1))) void*)(gp),  \
    (__attribute__((address_space(3))) void*)(lp), 16, 0, 0)

static __device__ __forceinline__ unsigned short bfbits(float f) {
    return __builtin_bit_cast(unsigned short, (bf16_t)f);
}

// ---------------------------------------------------------------------------
// Fused prelude: [0,768) wgen | [768,2816) support | [2816,4864) y0.
// All three are independent; fusing overlaps their latency/BW phases.
// Shared union: 64*65 floats = 16.6 KB.
// ---------------------------------------------------------------------------
__global__ __launch_bounds__(256) void prelude_kernel(
    const float* __restrict__ x,  const float* __restrict__ E,
    const float* __restrict__ wp, bf16_t* __restrict__ Y0,
    bf16_t* __restrict__ Sb,      bf16_t* __restrict__ Wt) {
    __shared__ float smem[64 * 65];
    const int bid = blockIdx.x;
    const int tid = threadIdx.x;

    if (bid < 768) {
        // ================= wgen: Wt[n][oki] = sum_d E[n,d]*wp[d][ki][o] ====
        // grid (12 oki-slices x 64 n-chunks); NT stores (Wt is stream-once).
        float (*sE)[16] = reinterpret_cast<float(*)[16]>(smem);
        const int n0   = (bid / 12) * 32;
        const int oki0 = (bid % 12) * 1024 + 4 * tid;
        const int o = oki0 / WKI, r0 = oki0 % WKI;

        if (tid < 128) {
            const int node = tid >> 2, q = tid & 3;
            *reinterpret_cast<float4*>(&sE[node][q * 4]) =
                *reinterpret_cast<const float4*>(E + (size_t)(n0 + node) * EMB + q * 4);
        }
        float w[4][EMB];
#pragma unroll
        for (int d = 0; d < EMB; ++d)
#pragma unroll
            for (int j = 0; j < 4; ++j)
                w[j][d] = wp[(size_t)(d * WKI + r0 + j) * 64 + o];
        __syncthreads();

#pragma unroll 2
        for (int nn = 0; nn < 32; ++nn) {
            float4 e0 = *reinterpret_cast<const float4*>(&sE[nn][0]);
            float4 e1 = *reinterpret_cast<const float4*>(&sE[nn][4]);
            float4 e2 = *reinterpret_cast<const float4*>(&sE[nn][8]);
            float4 e3 = *reinterpret_cast<const float4*>(&sE[nn][12]);
            float en[EMB] = {e0.x,e0.y,e0.z,e0.w, e1.x,e1.y,e1.z,e1.w,
                             e2.x,e2.y,e2.z,e2.w, e3.x,e3.y,e3.z,e3.w};
            float a[4] = {};
#pragma unroll
            for (int d = 0; d < EMB; ++d)
#pragma unroll
                for (int j = 0; j < 4; ++j) a[j] += en[d] * w[j][d];
            ushort4 pk;
            pk.x = bfbits(a[0]); pk.y = bfbits(a[1]);
            pk.z = bfbits(a[2]); pk.w = bfbits(a[3]);
            __builtin_nontemporal_store(
                __builtin_bit_cast(u32x2, pk),
                reinterpret_cast<u32x2*>(Wt + (size_t)(n0 + nn) * 12288 + oki0));
        }
    } else if (bid < 2816) {
        // ================= support: Sb[n,:] = softmax(relu(E[n]@E^T)) ======
        float* vals = smem;                 // [0,2048)
        float* red  = smem + 2048;          // [2048,2052)
        const int n = bid - 768;

        float en[EMB];
#pragma unroll
        for (int d = 0; d < EMB; ++d) en[d] = E[n * EMB + d];

        float lmax = -1e30f;
        for (int m = tid; m < NN; m += 256) {
            const float4* em = reinterpret_cast<const float4*>(E + m * EMB);
            float dot = 0.f;
#pragma unroll
            for (int q = 0; q < EMB / 4; ++q) {
                float4 v = em[q];
                dot += en[q*4+0]*v.x + en[q*4+1]*v.y + en[q*4+2]*v.z + en[q*4+3]*v.w;
            }
            float r = fmaxf(dot, 0.f);
            vals[m] = r;
            lmax = fmaxf(lmax, r);
        }
#pragma unroll
        for (int off = 32; off > 0; off >>= 1)
            lmax = fmaxf(lmax, __shfl_down(lmax, off, 64));
        if ((tid & 63) == 0) red[tid >> 6] = lmax;
        __syncthreads();
        const float gmax = fmaxf(fmaxf(red[0], red[1]), fmaxf(red[2], red[3]));
        __syncthreads();

        float lsum = 0.f;
        for (int m = tid; m < NN; m += 256) {
            float e = expf(vals[m] - gmax);
            vals[m] = e;
            lsum += e;
        }
#pragma unroll
        for (int off = 32; off > 0; off >>= 1)
            lsum += __shfl_down(lsum, off, 64);
        if ((tid & 63) == 0) red[tid >> 6] = lsum;
        __syncthreads();
        const float inv = 1.f / (red[0] + red[1] + red[2] + red[3]);

        for (int m = tid; m < NN; m += 256)
            Sb[(size_t)n * NN + m] = (bf16_t)(vals[m] * inv);
    } else {
        // ================= y0: Y0[b*64+c][n] = x[b][n][c] ==================
        float (*tile)[65] = reinterpret_cast<float(*)[65]>(smem);
        const int yb = bid - 2816;
        const int n0 = (yb & 31) * 64, b = yb >> 5;
        const int c = tid & 63, nn0 = tid >> 6;
        const float* src = x + ((size_t)b * NN + n0) * CIN + c;
#pragma unroll
        for (int p = 0; p < 16; ++p) {
            int nn = nn0 + p * 4;
            tile[nn][c] = src[(size_t)nn * CIN];
        }
        __syncthreads();
        const int cc = tid >> 2, q = tid & 3;
        bf16_t* dst = Y0 + (size_t)(b * 64 + cc) * NN + n0 + q * 16;
#pragma unroll
        for (int s4 = 0; s4 < 4; ++s4) {
            ushort4 pk;
            pk.x = bfbits(tile[q * 16 + s4 * 4 + 0][cc]);
            pk.y = bfbits(tile[q * 16 + s4 * 4 + 1][cc]);
            pk.z = bfbits(tile[q * 16 + s4 * 4 + 2][cc]);
            pk.w = bfbits(tile[q * 16 + s4 * 4 + 3][cc]);
            *reinterpret_cast<ushort4*>(dst + s4 * 4) = pk;
        }
    }
}

// ---------------------------------------------------------------------------
// C(4096x2048) = A @ Bt^T (both K=node contiguous, bf16).
// MODE 0: writes Cj (j-major, scale 1) AND GT (node-major, scale 1)
// MODE 1: writes only GT (node-major, scale 2)
// ---------------------------------------------------------------------------
template<int MODE>
__global__ __launch_bounds__(256) void gemm_bt(
    const bf16_t* __restrict__ A, const bf16_t* __restrict__ Bt,
    bf16_t* __restrict__ Cj, bf16_t* __restrict__ GT) {
    __shared__ bf16_t smem[128 * 136];    // 34.8 KB; union of {As,Bs} and T
    bf16_t* As = smem;                    // 128*32
    bf16_t* Bs = smem + 4096;             // 128*32
    bf16_t* T  = smem;                    // 128*136 (epilogue reuse)
    const int tid  = threadIdx.x;
    const int wave = tid >> 6, lane = tid & 63;
    const int pBlk = blockIdx.x * 128;    // node cols
    const int mBlk = blockIdx.y * 128;    // j rows
    const int K = NN;

    const bf16_t* aSrc = A  + (size_t)(mBlk + wave * 32 + (lane >> 2)) * K + (lane & 3) * 8;
    const bf16_t* bSrc = Bt + (size_t)(pBlk + wave * 32 + (lane >> 2)) * K + (lane & 3) * 8;
    bf16_t* aDst = As + wave * 1024;
    bf16_t* bDst = Bs + wave * 1024;

    f32x4 acc[4][4] = {};
    const int wr = wave >> 1, wc = wave & 1;
    const int lrow = lane & 15, lk = (lane >> 4) * 8;

    for (int k0 = 0; k0 < K; k0 += 32) {
        GLOAD16(aSrc + k0,                  aDst);
        GLOAD16(aSrc + k0 + (size_t)16 * K, aDst + 512);
        GLOAD16(bSrc + k0,                  bDst);
        GLOAD16(bSrc + k0 + (size_t)16 * K, bDst + 512);
        __syncthreads();

        bf16x8 af[4], bb[4];
#pragma unroll
        for (int mf = 0; mf < 4; ++mf)
            af[mf] = *reinterpret_cast<const bf16x8*>(
                &As[(wr * 64 + mf * 16 + lrow) * 32 + lk]);
#pragma unroll
        for (int nf = 0; nf < 4; ++nf)
            bb[nf] = *reinterpret_cast<const bf16x8*>(
                &Bs[(wc * 64 + nf * 16 + lrow) * 32 + lk]);
#pragma unroll
        for (int mf = 0; mf < 4; ++mf)
#pragma unroll
            for (int nf = 0; nf < 4; ++nf)
                acc[mf][nf] = __builtin_amdgcn_mfma_f32_16x16x32_bf16(
                    af[mf], bb[nf], acc[mf][nf], 0, 0, 0);
        __syncthreads();
    }

    // epilogue. C/D layout: col = lane&15, row = (lane>>4)*4 + r  [m89]
    const int orow = (lane >> 4) * 4, ocol = lane & 15;
    if (MODE == 0) {
#pragma unroll
        for (int mf = 0; mf < 4; ++mf)
#pragma unroll
            for (int nf = 0; nf < 4; ++nf)
#pragma unroll
                for (int r = 0; r < 4; ++r) {
                    size_t row = (size_t)(mBlk + wr * 64 + mf * 16 + orow + r);
                    size_t col = (size_t)(pBlk + wc * 64 + nf * 16 + ocol);
                    Cj[row * NN + col] = (bf16_t)acc[mf][nf][r];
                }
    }
    const float scale = (MODE == 1) ? 2.f : 1.f;
#pragma unroll
    for (int mf = 0; mf < 4; ++mf)
#pragma unroll
        for (int nf = 0; nf < 4; ++nf)
#pragma unroll
            for (int r = 0; r < 4; ++r) {
                int trow = wr * 64 + mf * 16 + orow + r;   // local j
                int tcol = wc * 64 + nf * 16 + ocol;       // local n
                T[(size_t)tcol * 136 + trow] = (bf16_t)(scale * acc[mf][nf][r]);
            }
    __syncthreads();
    {
        const int row = tid >> 1, half = tid & 1;          // local n, j-half
        const bf16_t* src = T + (size_t)row * 136 + half * 64;
        bf16_t* dst = GT + (size_t)(pBlk + row) * JDIM + mBlk + half * 64;
#pragma unroll
        for (int s = 0; s < 8; ++s)
            *reinterpret_cast<uint4*>(dst + s * 8) =
                *reinterpret_cast<const uint4*>(src + s * 8);
    }
}

// ---------------------------------------------------------------------------
// Final grouped matmul, MFMA. One node per block (grid NN).
// Wt read + out write are stream-once -> nontemporal (no L2 allocate).
// ---------------------------------------------------------------------------
__global__ __launch_bounds__(256) void gconv_kernel(
    const float* __restrict__ x,   const float* __restrict__ E,
    const float* __restrict__ bp,  const bf16_t* __restrict__ G1T,
    const bf16_t* __restrict__ G2T, const bf16_t* __restrict__ Wt,
    float* __restrict__ out) {
    __shared__ bf16_t g[64][200];          // 25.6 KB
    const int n = blockIdx.x;
    const int tid = threadIdx.x, wave = tid >> 6, lane = tid & 63;
    const int lrow = lane & 15, lk = (lane >> 4) * 8;
    const int o = wave * 16 + lrow;        // this lane's output col

    // ---- prefetch Wt fragments (NT) + bias (independent of LDS) ----
    const bf16_t* wtn = Wt + (size_t)n * 12288 + (size_t)o * WKI;
    bf16x8 bb[6];
#pragma unroll
    for (int ks = 0; ks < 6; ++ks)
        bb[ks] = __builtin_bit_cast(bf16x8, __builtin_nontemporal_load(
            reinterpret_cast<const u32x4*>(wtn + ks * 32 + lk)));
    float bo = 0.f;
    {
        const float* en = E + (size_t)n * EMB;
#pragma unroll
        for (int d = 0; d < EMB; ++d) bo += en[d] * bp[d * COUT + o];
    }

    // ---- stage g (cooperative) ----
#pragma unroll
    for (int p = 0; p < 2; ++p) {
        int idx = p * 256 + tid;                 // 0..511
        int b = idx >> 3, ic = (idx & 7) * 8;
        const float4* xs = reinterpret_cast<const float4*>(
            x + ((size_t)b * NN + n) * CIN + ic);
        float4 x0 = xs[0], x1 = xs[1];
        uint4 g1v = *reinterpret_cast<const uint4*>(G1T + (size_t)n * JDIM + idx * 8);
        uint4 g2v = *reinterpret_cast<const uint4*>(G2T + (size_t)n * JDIM + idx * 8);
        float xv[8] = {x0.x, x0.y, x0.z, x0.w, x1.x, x1.y, x1.z, x1.w};
        const bf16_t* g2p = reinterpret_cast<const bf16_t*>(&g2v);
        ushort4 g0b[2], g2b[2];
#pragma unroll
        for (int e = 0; e < 8; ++e) {
            ((unsigned short*)g0b)[e] = bfbits(xv[e]);
            ((unsigned short*)g2b)[e] = bfbits((float)g2p[e] - xv[e]);
        }
        *reinterpret_cast<uint4*>(&g[b][ic])       = *reinterpret_cast<uint4*>(g0b);
        *reinterpret_cast<uint4*>(&g[b][64 + ic])  = g1v;
        *reinterpret_cast<uint4*>(&g[b][128 + ic]) = *reinterpret_cast<uint4*>(g2b);
    }
    __syncthreads();

    // ---- compute: 64x16 output slice per wave, K=192 ----
    f32x4 acc[4] = {};
#pragma unroll
    for (int ks = 0; ks < 6; ++ks)
#pragma unroll
        for (int mf = 0; mf < 4; ++mf) {
            bf16x8 af = *reinterpret_cast<const bf16x8*>(&g[mf * 16 + lrow][ks * 32 + lk]);
            acc[mf] = __builtin_amdgcn_mfma_f32_16x16x32_bf16(af, bb[ks], acc[mf], 0, 0, 0);
        }
#pragma unroll
    for (int mf = 0; mf < 4; ++mf)
#pragma unroll
        for (int r = 0; r < 4; ++r) {
            int b = mf * 16 + (lane >> 4) * 4 + r;
            __builtin_nontemporal_store(acc[mf][r] + bo,
                &out[((size_t)b * NN + n) * COUT + o]);
        }
}

// ---------------------------------------------------------------------------
extern "C" void kernel_launch(void* const* d_in, const int* in_sizes, int n_in,
                              void* d_out, int out_size, void* d_ws, size_t ws_size,
                              hipStream_t stream) {
    const float* x  = (const float*)d_in[0];   // (64,2048,64)
    const float* E  = (const float*)d_in[1];   // (2048,16)
    const float* wp = (const float*)d_in[2];   // (16,3,64,64)
    const float* bp = (const float*)d_in[3];   // (16,64)
    float* out = (float*)d_out;

    bf16_t* ws = (bf16_t*)d_ws;
    bf16_t* Wt  = ws;                          // 2048*12288      = 48 MB
    bf16_t* Sb  = Wt + (size_t)NN * 12288;     // 2048*2048       =  8 MB
    bf16_t* Y0  = Sb + (size_t)NN * NN;        // 4096*2048       = 16 MB
    bf16_t* Y1  = Y0 + (size_t)JDIM * NN;      // 16 MB
    bf16_t* G1T = Y1 + (size_t)JDIM * NN;      // 16 MB  (total 104 MB)
    bf16_t* G2T = Y0;                          // alias: Y0 dead after gemm<0>

    prelude_kernel<<<768 + 2048 + 2048, 256, 0, stream>>>(x, E, wp, Y0, Sb, Wt);

    dim3 ggrid(NN / 128, JDIM / 128);          // 16 x 32 = 512 blocks
    gemm_bt<0><<<ggrid, 256, 0, stream>>>(Y0, Sb, Y1, G1T);
    gemm_bt<1><<<ggrid, 256, 0, stream>>>(Y1, Sb, nullptr, G2T);

    gconv_kernel<<<NN, 256, 0, stream>>>(x, E, bp, G1T, G2T, Wt, out);
}

// Round 7
// 263.475 us; speedup vs baseline: 1.0735x; 1.0025x over previous
//
#include <hip/hip_runtime.h>
#include <math.h>

// AVWGCN: B=64, N=2048, C_IN=C_OUT=64, CHEB_K=3, EMBED=16
#define NN    2048
#define BATCH 64
#define CIN   64
#define COUT  64
#define EMB   16
#define JDIM  4096   // BATCH*CIN
#define WKI   192    // CHEB_K*CIN

typedef __bf16 bf16_t;
typedef __bf16 bf16x8 __attribute__((ext_vector_type(8)));
typedef float  f32x4  __attribute__((ext_vector_type(4)));
typedef unsigned int u32x4 __attribute__((ext_vector_type(4)));

#define GLOAD16(gp, lp) __builtin_amdgcn_global_load_lds( \
    (const __attribute__((address_space(1))) void*)(gp),  \
    (__attribute__((address_space(3))) void*)(lp), 16, 0, 0)

static __device__ __forceinline__ unsigned short bfbits(float f) {
    return __builtin_bit_cast(unsigned short, (bf16_t)f);
}

// ---------------------------------------------------------------------------
// wgen v4: Wt[n][oki] = sum_d E[n,d]*wp[d][ki][o], oki = o*192 + ki.
// Fix for the uncoalesced wp gather (the ~60us wall of v1-v3): the block's
// wp window (4 o-cols x 192 ki x 16 d = 49KB fp32) is loaded COALESCED into
// LDS once (16B segments, no redundancy), then threads read their per-thread
// w[2][16] slice from LDS. Math identical to v3 (fp32 wp, fp32 accum).
// Grid: 24 oki-slices x 64 node-chunks = 1536 blocks. NT 4B stores.
// ---------------------------------------------------------------------------
__global__ __launch_bounds__(256) void wgen_kernel(
    const float* __restrict__ E, const float* __restrict__ wp,
    bf16_t* __restrict__ Wt) {
    __shared__ float wL[3072 * 4];         // [dr = d*192+r][oo<4]  49.2 KB
    __shared__ float sE[32][16];           // 2 KB
    const int s  = blockIdx.x % 24;        // oki slice (512 wide)
    const int n0 = (blockIdx.x / 24) * 32; // node chunk
    const int t  = threadIdx.x;
    const int oki0 = s * 512 + 2 * t;      // even -> both outputs same o
    const int o = oki0 / WKI, r0 = oki0 % WKI;
    const int o_lo = (s * 512) / WKI;      // window base; o - o_lo in [0,3]

    // stage E[n0:n0+32]
    if (t < 128) {
        const int node = t >> 2, q = t & 3;
        *reinterpret_cast<float4*>(&sE[node][q * 4]) =
            *reinterpret_cast<const float4*>(E + (size_t)(n0 + node) * EMB + q * 4);
    }
    // coalesced wp-window load: lane-groups of 4 -> 16B segments
    {
        const int oo  = t & 3;
        const int col = min(o_lo + oo, 63);        // clamp (unused slots only)
#pragma unroll
        for (int i = 0; i < 48; ++i) {
            int dr = (t >> 2) + i * 64;            // 0..3071
            wL[dr * 4 + oo] = wp[(size_t)dr * 64 + col];
        }
    }
    __syncthreads();

    // per-thread weight slice from LDS (one-time)
    float w[2][EMB];
#pragma unroll
    for (int d = 0; d < EMB; ++d) {
        w[0][d] = wL[(d * WKI + r0) * 4 + (o - o_lo)];
        w[1][d] = wL[(d * WKI + r0 + 1) * 4 + (o - o_lo)];
    }

#pragma unroll 2
    for (int nn = 0; nn < 32; ++nn) {
        float4 e0 = *reinterpret_cast<const float4*>(&sE[nn][0]);
        float4 e1 = *reinterpret_cast<const float4*>(&sE[nn][4]);
        float4 e2 = *reinterpret_cast<const float4*>(&sE[nn][8]);
        float4 e3 = *reinterpret_cast<const float4*>(&sE[nn][12]);
        float en[EMB] = {e0.x,e0.y,e0.z,e0.w, e1.x,e1.y,e1.z,e1.w,
                         e2.x,e2.y,e2.z,e2.w, e3.x,e3.y,e3.z,e3.w};
        float a0 = 0.f, a1 = 0.f;
#pragma unroll
        for (int d = 0; d < EMB; ++d) {
            a0 += en[d] * w[0][d];
            a1 += en[d] * w[1][d];
        }
        unsigned int pk = (unsigned int)bfbits(a0) | ((unsigned int)bfbits(a1) << 16);
        __builtin_nontemporal_store(pk,
            reinterpret_cast<unsigned int*>(Wt + (size_t)(n0 + nn) * 12288 + oki0));
    }
}

// ---------------------------------------------------------------------------
// Fused support + y0: [0,2048) support rows | [2048,4096) y0 tiles.
// ---------------------------------------------------------------------------
__global__ __launch_bounds__(256) void sy_kernel(
    const float* __restrict__ x, const float* __restrict__ E,
    bf16_t* __restrict__ Y0, bf16_t* __restrict__ Sb) {
    __shared__ float smem[64 * 65];
    const int bid = blockIdx.x;
    const int tid = threadIdx.x;

    if (bid < 2048) {
        // ============ support: Sb[n,:] = softmax(relu(E[n]@E^T)) ===========
        float* vals = smem;
        float* red  = smem + 2048;
        const int n = bid;

        float en[EMB];
#pragma unroll
        for (int d = 0; d < EMB; ++d) en[d] = E[n * EMB + d];

        float lmax = -1e30f;
        for (int m = tid; m < NN; m += 256) {
            const float4* em = reinterpret_cast<const float4*>(E + m * EMB);
            float dot = 0.f;
#pragma unroll
            for (int q = 0; q < EMB / 4; ++q) {
                float4 v = em[q];
                dot += en[q*4+0]*v.x + en[q*4+1]*v.y + en[q*4+2]*v.z + en[q*4+3]*v.w;
            }
            float r = fmaxf(dot, 0.f);
            vals[m] = r;
            lmax = fmaxf(lmax, r);
        }
#pragma unroll
        for (int off = 32; off > 0; off >>= 1)
            lmax = fmaxf(lmax, __shfl_down(lmax, off, 64));
        if ((tid & 63) == 0) red[tid >> 6] = lmax;
        __syncthreads();
        const float gmax = fmaxf(fmaxf(red[0], red[1]), fmaxf(red[2], red[3]));
        __syncthreads();

        float lsum = 0.f;
        for (int m = tid; m < NN; m += 256) {
            float e = expf(vals[m] - gmax);
            vals[m] = e;
            lsum += e;
        }
#pragma unroll
        for (int off = 32; off > 0; off >>= 1)
            lsum += __shfl_down(lsum, off, 64);
        if ((tid & 63) == 0) red[tid >> 6] = lsum;
        __syncthreads();
        const float inv = 1.f / (red[0] + red[1] + red[2] + red[3]);

        for (int m = tid; m < NN; m += 256)
            Sb[(size_t)n * NN + m] = (bf16_t)(vals[m] * inv);
    } else {
        // ============ y0: Y0[b*64+c][n] = x[b][n][c] =======================
        float (*tile)[65] = reinterpret_cast<float(*)[65]>(smem);
        const int yb = bid - 2048;
        const int n0 = (yb & 31) * 64, b = yb >> 5;
        const int c = tid & 63, nn0 = tid >> 6;
        const float* src = x + ((size_t)b * NN + n0) * CIN + c;
#pragma unroll
        for (int p = 0; p < 16; ++p) {
            int nn = nn0 + p * 4;
            tile[nn][c] = src[(size_t)nn * CIN];
        }
        __syncthreads();
        const int cc = tid >> 2, q = tid & 3;
        bf16_t* dst = Y0 + (size_t)(b * 64 + cc) * NN + n0 + q * 16;
#pragma unroll
        for (int s4 = 0; s4 < 4; ++s4) {
            ushort4 pk;
            pk.x = bfbits(tile[q * 16 + s4 * 4 + 0][cc]);
            pk.y = bfbits(tile[q * 16 + s4 * 4 + 1][cc]);
            pk.z = bfbits(tile[q * 16 + s4 * 4 + 2][cc]);
            pk.w = bfbits(tile[q * 16 + s4 * 4 + 3][cc]);
            *reinterpret_cast<ushort4*>(dst + s4 * 4) = pk;
        }
    }
}

// ---------------------------------------------------------------------------
// C(4096x2048) = A @ Bt^T (both K=node contiguous, bf16).
// MODE 0: writes Cj (j-major, scale 1) AND GT (node-major, scale 1)
// MODE 1: writes only GT (node-major, scale 2)
// ---------------------------------------------------------------------------
template<int MODE>
__global__ __launch_bounds__(256) void gemm_bt(
    const bf16_t* __restrict__ A, const bf16_t* __restrict__ Bt,
    bf16_t* __restrict__ Cj, bf16_t* __restrict__ GT) {
    __shared__ bf16_t smem[128 * 136];    // 34.8 KB; union of {As,Bs} and T
    bf16_t* As = smem;                    // 128*32
    bf16_t* Bs = smem + 4096;             // 128*32
    bf16_t* T  = smem;                    // 128*136 (epilogue reuse)
    const int tid  = threadIdx.x;
    const int wave = tid >> 6, lane = tid & 63;
    const int pBlk = blockIdx.x * 128;    // node cols
    const int mBlk = blockIdx.y * 128;    // j rows
    const int K = NN;

    const bf16_t* aSrc = A  + (size_t)(mBlk + wave * 32 + (lane >> 2)) * K + (lane & 3) * 8;
    const bf16_t* bSrc = Bt + (size_t)(pBlk + wave * 32 + (lane >> 2)) * K + (lane & 3) * 8;
    bf16_t* aDst = As + wave * 1024;
    bf16_t* bDst = Bs + wave * 1024;

    f32x4 acc[4][4] = {};
    const int wr = wave >> 1, wc = wave & 1;
    const int lrow = lane & 15, lk = (lane >> 4) * 8;

    for (int k0 = 0; k0 < K; k0 += 32) {
        GLOAD16(aSrc + k0,                  aDst);
        GLOAD16(aSrc + k0 + (size_t)16 * K, aDst + 512);
        GLOAD16(bSrc + k0,                  bDst);
        GLOAD16(bSrc + k0 + (size_t)16 * K, bDst + 512);
        __syncthreads();

        bf16x8 af[4], bb[4];
#pragma unroll
        for (int mf = 0; mf < 4; ++mf)
            af[mf] = *reinterpret_cast<const bf16x8*>(
                &As[(wr * 64 + mf * 16 + lrow) * 32 + lk]);
#pragma unroll
        for (int nf = 0; nf < 4; ++nf)
            bb[nf] = *reinterpret_cast<const bf16x8*>(
                &Bs[(wc * 64 + nf * 16 + lrow) * 32 + lk]);
#pragma unroll
        for (int mf = 0; mf < 4; ++mf)
#pragma unroll
            for (int nf = 0; nf < 4; ++nf)
                acc[mf][nf] = __builtin_amdgcn_mfma_f32_16x16x32_bf16(
                    af[mf], bb[nf], acc[mf][nf], 0, 0, 0);
        __syncthreads();
    }

    // epilogue. C/D layout: col = lane&15, row = (lane>>4)*4 + r  [m89]
    const int orow = (lane >> 4) * 4, ocol = lane & 15;
    if (MODE == 0) {
#pragma unroll
        for (int mf = 0; mf < 4; ++mf)
#pragma unroll
            for (int nf = 0; nf < 4; ++nf)
#pragma unroll
                for (int r = 0; r < 4; ++r) {
                    size_t row = (size_t)(mBlk + wr * 64 + mf * 16 + orow + r);
                    size_t col = (size_t)(pBlk + wc * 64 + nf * 16 + ocol);
                    Cj[row * NN + col] = (bf16_t)acc[mf][nf][r];
                }
    }
    const float scale = (MODE == 1) ? 2.f : 1.f;
#pragma unroll
    for (int mf = 0; mf < 4; ++mf)
#pragma unroll
        for (int nf = 0; nf < 4; ++nf)
#pragma unroll
            for (int r = 0; r < 4; ++r) {
                int trow = wr * 64 + mf * 16 + orow + r;   // local j
                int tcol = wc * 64 + nf * 16 + ocol;       // local n
                T[(size_t)tcol * 136 + trow] = (bf16_t)(scale * acc[mf][nf][r]);
            }
    __syncthreads();
    {
        const int row = tid >> 1, half = tid & 1;          // local n, j-half
        const bf16_t* src = T + (size_t)row * 136 + half * 64;
        bf16_t* dst = GT + (size_t)(pBlk + row) * JDIM + mBlk + half * 64;
#pragma unroll
        for (int s = 0; s < 8; ++s)
            *reinterpret_cast<uint4*>(dst + s * 8) =
                *reinterpret_cast<const uint4*>(src + s * 8);
    }
}

// ---------------------------------------------------------------------------
// Final grouped matmul, MFMA. One node per block (grid NN).
// Wt read + out write are stream-once -> nontemporal.
// ---------------------------------------------------------------------------
__global__ __launch_bounds__(256) void gconv_kernel(
    const float* __restrict__ x,   const float* __restrict__ E,
    const float* __restrict__ bp,  const bf16_t* __restrict__ G1T,
    const bf16_t* __restrict__ G2T, const bf16_t* __restrict__ Wt,
    float* __restrict__ out) {
    __shared__ bf16_t g[64][200];          // 25.6 KB
    const int n = blockIdx.x;
    const int tid = threadIdx.x, wave = tid >> 6, lane = tid & 63;
    const int lrow = lane & 15, lk = (lane >> 4) * 8;
    const int o = wave * 16 + lrow;        // this lane's output col

    // ---- prefetch Wt fragments (NT) + bias (independent of LDS) ----
    const bf16_t* wtn = Wt + (size_t)n * 12288 + (size_t)o * WKI;
    bf16x8 bb[6];
#pragma unroll
    for (int ks = 0; ks < 6; ++ks)
        bb[ks] = __builtin_bit_cast(bf16x8, __builtin_nontemporal_load(
            reinterpret_cast<const u32x4*>(wtn + ks * 32 + lk)));
    float bo = 0.f;
    {
        const float* en = E + (size_t)n * EMB;
#pragma unroll
        for (int d = 0; d < EMB; ++d) bo += en[d] * bp[d * COUT + o];
    }

    // ---- stage g (cooperative) ----
#pragma unroll
    for (int p = 0; p < 2; ++p) {
        int idx = p * 256 + tid;                 // 0..511
        int b = idx >> 3, ic = (idx & 7) * 8;
        const float4* xs = reinterpret_cast<const float4*>(
            x + ((size_t)b * NN + n) * CIN + ic);
        float4 x0 = xs[0], x1 = xs[1];
        uint4 g1v = *reinterpret_cast<const uint4*>(G1T + (size_t)n * JDIM + idx * 8);
        uint4 g2v = *reinterpret_cast<const uint4*>(G2T + (size_t)n * JDIM + idx * 8);
        float xv[8] = {x0.x, x0.y, x0.z, x0.w, x1.x, x1.y, x1.z, x1.w};
        const bf16_t* g2p = reinterpret_cast<const bf16_t*>(&g2v);
        ushort4 g0b[2], g2b[2];
#pragma unroll
        for (int e = 0; e < 8; ++e) {
            ((unsigned short*)g0b)[e] = bfbits(xv[e]);
            ((unsigned short*)g2b)[e] = bfbits((float)g2p[e] - xv[e]);
        }
        *reinterpret_cast<uint4*>(&g[b][ic])       = *reinterpret_cast<uint4*>(g0b);
        *reinterpret_cast<uint4*>(&g[b][64 + ic])  = g1v;
        *reinterpret_cast<uint4*>(&g[b][128 + ic]) = *reinterpret_cast<uint4*>(g2b);
    }
    __syncthreads();

    // ---- compute: 64x16 output slice per wave, K=192 ----
    f32x4 acc[4] = {};
#pragma unroll
    for (int ks = 0; ks < 6; ++ks)
#pragma unroll
        for (int mf = 0; mf < 4; ++mf) {
            bf16x8 af = *reinterpret_cast<const bf16x8*>(&g[mf * 16 + lrow][ks * 32 + lk]);
            acc[mf] = __builtin_amdgcn_mfma_f32_16x16x32_bf16(af, bb[ks], acc[mf], 0, 0, 0);
        }
#pragma unroll
    for (int mf = 0; mf < 4; ++mf)
#pragma unroll
        for (int r = 0; r < 4; ++r) {
            int b = mf * 16 + (lane >> 4) * 4 + r;
            __builtin_nontemporal_store(acc[mf][r] + bo,
                &out[((size_t)b * NN + n) * COUT + o]);
        }
}

// ---------------------------------------------------------------------------
extern "C" void kernel_launch(void* const* d_in, const int* in_sizes, int n_in,
                              void* d_out, int out_size, void* d_ws, size_t ws_size,
                              hipStream_t stream) {
    const float* x  = (const float*)d_in[0];   // (64,2048,64)
    const float* E  = (const float*)d_in[1];   // (2048,16)
    const float* wp = (const float*)d_in[2];   // (16,3,64,64)
    const float* bp = (const float*)d_in[3];   // (16,64)
    float* out = (float*)d_out;

    bf16_t* ws = (bf16_t*)d_ws;
    bf16_t* Wt  = ws;                          // 2048*12288      = 48 MB
    bf16_t* Sb  = Wt + (size_t)NN * 12288;     // 2048*2048       =  8 MB
    bf16_t* Y0  = Sb + (size_t)NN * NN;        // 4096*2048       = 16 MB
    bf16_t* Y1  = Y0 + (size_t)JDIM * NN;      // 16 MB
    bf16_t* G1T = Y1 + (size_t)JDIM * NN;      // 16 MB  (total 104 MB)
    bf16_t* G2T = Y0;                          // alias: Y0 dead after gemm<0>

    sy_kernel<<<4096, 256, 0, stream>>>(x, E, Y0, Sb);
    wgen_kernel<<<24 * 64, 256, 0, stream>>>(E, wp, Wt);

    dim3 ggrid(NN / 128, JDIM / 128);          // 16 x 32 = 512 blocks
    gemm_bt<0><<<ggrid, 256, 0, stream>>>(Y0, Sb, Y1, G1T);
    gemm_bt<1><<<ggrid, 256, 0, stream>>>(Y1, Sb, nullptr, G2T);

    gconv_kernel<<<NN, 256, 0, stream>>>(x, E, bp, G1T, G2T, Wt, out);
}

// Round 8
// 253.944 us; speedup vs baseline: 1.1137x; 1.0375x over previous
//
#include <hip/hip_runtime.h>
#include <math.h>

// AVWGCN: B=64, N=2048, C_IN=C_OUT=64, CHEB_K=3, EMBED=16
#define NN    2048
#define BATCH 64
#define CIN   64
#define COUT  64
#define EMB   16
#define JDIM  4096   // BATCH*CIN
#define WKI   192    // CHEB_K*CIN

typedef __bf16 bf16_t;
typedef __bf16 bf16x8 __attribute__((ext_vector_type(8)));
typedef float  f32x4  __attribute__((ext_vector_type(4)));

#define GLOAD16(gp, lp) __builtin_amdgcn_global_load_lds( \
    (const __attribute__((address_space(1))) void*)(gp),  \
    (__attribute__((address_space(3))) void*)(lp), 16, 0, 0)

static __device__ __forceinline__ unsigned short bfbits(float f) {
    return __builtin_bit_cast(unsigned short, (bf16_t)f);
}

// ---------------------------------------------------------------------------
// Fused support + y0: [0,2048) support rows | [2048,4096) y0 tiles.
// ---------------------------------------------------------------------------
__global__ __launch_bounds__(256) void sy_kernel(
    const float* __restrict__ x, const float* __restrict__ E,
    bf16_t* __restrict__ Y0, bf16_t* __restrict__ Sb) {
    __shared__ float smem[64 * 65];
    const int bid = blockIdx.x;
    const int tid = threadIdx.x;

    if (bid < 2048) {
        // ============ support: Sb[n,:] = softmax(relu(E[n]@E^T)) ===========
        float* vals = smem;
        float* red  = smem + 2048;
        const int n = bid;

        float en[EMB];
#pragma unroll
        for (int d = 0; d < EMB; ++d) en[d] = E[n * EMB + d];

        float lmax = -1e30f;
        for (int m = tid; m < NN; m += 256) {
            const float4* em = reinterpret_cast<const float4*>(E + m * EMB);
            float dot = 0.f;
#pragma unroll
            for (int q = 0; q < EMB / 4; ++q) {
                float4 v = em[q];
                dot += en[q*4+0]*v.x + en[q*4+1]*v.y + en[q*4+2]*v.z + en[q*4+3]*v.w;
            }
            float r = fmaxf(dot, 0.f);
            vals[m] = r;
            lmax = fmaxf(lmax, r);
        }
#pragma unroll
        for (int off = 32; off > 0; off >>= 1)
            lmax = fmaxf(lmax, __shfl_down(lmax, off, 64));
        if ((tid & 63) == 0) red[tid >> 6] = lmax;
        __syncthreads();
        const float gmax = fmaxf(fmaxf(red[0], red[1]), fmaxf(red[2], red[3]));
        __syncthreads();

        float lsum = 0.f;
        for (int m = tid; m < NN; m += 256) {
            float e = expf(vals[m] - gmax);
            vals[m] = e;
            lsum += e;
        }
#pragma unroll
        for (int off = 32; off > 0; off >>= 1)
            lsum += __shfl_down(lsum, off, 64);
        if ((tid & 63) == 0) red[tid >> 6] = lsum;
        __syncthreads();
        const float inv = 1.f / (red[0] + red[1] + red[2] + red[3]);

        for (int m = tid; m < NN; m += 256)
            Sb[(size_t)n * NN + m] = (bf16_t)(vals[m] * inv);
    } else {
        // ============ y0: Y0[b*64+c][n] = x[b][n][c] =======================
        float (*tile)[65] = reinterpret_cast<float(*)[65]>(smem);
        const int yb = bid - 2048;
        const int n0 = (yb & 31) * 64, b = yb >> 5;
        const int c = tid & 63, nn0 = tid >> 6;
        const float* src = x + ((size_t)b * NN + n0) * CIN + c;
#pragma unroll
        for (int p = 0; p < 16; ++p) {
            int nn = nn0 + p * 4;
            tile[nn][c] = src[(size_t)nn * CIN];
        }
        __syncthreads();
        const int cc = tid >> 2, q = tid & 3;
        bf16_t* dst = Y0 + (size_t)(b * 64 + cc) * NN + n0 + q * 16;
#pragma unroll
        for (int s4 = 0; s4 < 4; ++s4) {
            ushort4 pk;
            pk.x = bfbits(tile[q * 16 + s4 * 4 + 0][cc]);
            pk.y = bfbits(tile[q * 16 + s4 * 4 + 1][cc]);
            pk.z = bfbits(tile[q * 16 + s4 * 4 + 2][cc]);
            pk.w = bfbits(tile[q * 16 + s4 * 4 + 3][cc]);
            *reinterpret_cast<ushort4*>(dst + s4 * 4) = pk;
        }
    }
}

// ---------------------------------------------------------------------------
// HETEROGENEOUS kernel: blocks [0,512) = gemm<0> tiles (Y1 = Y0@S^T, writes
// Cj j-major AND GT node-major); blocks [512,2048) = wgen v4 (Wt gen).
// wgen is independent of the GEMM -> its memory-wall time hides under the
// GEMM's spare BW/issue slots instead of serializing on the stream.
// LDS union: max(gemm 34.8KB, wgen 51.2KB) = 51.2KB.
// ---------------------------------------------------------------------------
__global__ __launch_bounds__(256) void gemm0_wgen_kernel(
    const bf16_t* __restrict__ A, const bf16_t* __restrict__ Bt,
    bf16_t* __restrict__ Cj, bf16_t* __restrict__ GT,
    const float* __restrict__ E, const float* __restrict__ wp,
    bf16_t* __restrict__ Wt) {
    __shared__ float smemF[12800];         // 51.2 KB union
    const int bid = blockIdx.x;
    const int tid = threadIdx.x;

    if (bid < 512) {
        // =================== gemm<0> path (MODE 0) =========================
        bf16_t* As = reinterpret_cast<bf16_t*>(smemF);     // 128*32
        bf16_t* Bs = As + 4096;                            // 128*32
        bf16_t* T  = As;                                   // 128*136 epilogue
        const int wave = tid >> 6, lane = tid & 63;
        const int pBlk = (bid & 15) * 128;   // node cols
        const int mBlk = (bid >> 4) * 128;   // j rows
        const int K = NN;

        const bf16_t* aSrc = A  + (size_t)(mBlk + wave * 32 + (lane >> 2)) * K + (lane & 3) * 8;
        const bf16_t* bSrc = Bt + (size_t)(pBlk + wave * 32 + (lane >> 2)) * K + (lane & 3) * 8;
        bf16_t* aDst = As + wave * 1024;
        bf16_t* bDst = Bs + wave * 1024;

        f32x4 acc[4][4] = {};
        const int wr = wave >> 1, wc = wave & 1;
        const int lrow = lane & 15, lk = (lane >> 4) * 8;

        for (int k0 = 0; k0 < K; k0 += 32) {
            GLOAD16(aSrc + k0,                  aDst);
            GLOAD16(aSrc + k0 + (size_t)16 * K, aDst + 512);
            GLOAD16(bSrc + k0,                  bDst);
            GLOAD16(bSrc + k0 + (size_t)16 * K, bDst + 512);
            __syncthreads();

            bf16x8 af[4], bb[4];
#pragma unroll
            for (int mf = 0; mf < 4; ++mf)
                af[mf] = *reinterpret_cast<const bf16x8*>(
                    &As[(wr * 64 + mf * 16 + lrow) * 32 + lk]);
#pragma unroll
            for (int nf = 0; nf < 4; ++nf)
                bb[nf] = *reinterpret_cast<const bf16x8*>(
                    &Bs[(wc * 64 + nf * 16 + lrow) * 32 + lk]);
#pragma unroll
            for (int mf = 0; mf < 4; ++mf)
#pragma unroll
                for (int nf = 0; nf < 4; ++nf)
                    acc[mf][nf] = __builtin_amdgcn_mfma_f32_16x16x32_bf16(
                        af[mf], bb[nf], acc[mf][nf], 0, 0, 0);
            __syncthreads();
        }

        const int orow = (lane >> 4) * 4, ocol = lane & 15;
#pragma unroll
        for (int mf = 0; mf < 4; ++mf)
#pragma unroll
            for (int nf = 0; nf < 4; ++nf)
#pragma unroll
                for (int r = 0; r < 4; ++r) {
                    size_t row = (size_t)(mBlk + wr * 64 + mf * 16 + orow + r);
                    size_t col = (size_t)(pBlk + wc * 64 + nf * 16 + ocol);
                    Cj[row * NN + col] = (bf16_t)acc[mf][nf][r];
                }
#pragma unroll
        for (int mf = 0; mf < 4; ++mf)
#pragma unroll
            for (int nf = 0; nf < 4; ++nf)
#pragma unroll
                for (int r = 0; r < 4; ++r) {
                    int trow = wr * 64 + mf * 16 + orow + r;   // local j
                    int tcol = wc * 64 + nf * 16 + ocol;       // local n
                    T[(size_t)tcol * 136 + trow] = (bf16_t)acc[mf][nf][r];
                }
        __syncthreads();
        {
            const int row = tid >> 1, half = tid & 1;
            const bf16_t* src = T + (size_t)row * 136 + half * 64;
            bf16_t* dst = GT + (size_t)(pBlk + row) * JDIM + mBlk + half * 64;
#pragma unroll
            for (int s = 0; s < 8; ++s)
                *reinterpret_cast<uint4*>(dst + s * 8) =
                    *reinterpret_cast<const uint4*>(src + s * 8);
        }
    } else {
        // =================== wgen v4 path ==================================
        float* wL = smemF;                                     // 12288 floats
        float (*sE)[16] = reinterpret_cast<float(*)[16]>(smemF + 12288);
        const int wb = bid - 512;
        const int s  = wb % 24;                // oki slice (512 wide)
        const int n0 = (wb / 24) * 32;         // node chunk
        const int oki0 = s * 512 + 2 * tid;
        const int o = oki0 / WKI, r0 = oki0 % WKI;
        const int o_lo = (s * 512) / WKI;

        if (tid < 128) {
            const int node = tid >> 2, q = tid & 3;
            *reinterpret_cast<float4*>(&sE[node][q * 4]) =
                *reinterpret_cast<const float4*>(E + (size_t)(n0 + node) * EMB + q * 4);
        }
        {
            const int oo  = tid & 3;
            const int col = min(o_lo + oo, 63);
#pragma unroll
            for (int i = 0; i < 48; ++i) {
                int dr = (tid >> 2) + i * 64;
                wL[dr * 4 + oo] = wp[(size_t)dr * 64 + col];
            }
        }
        __syncthreads();

        float w[2][EMB];
#pragma unroll
        for (int d = 0; d < EMB; ++d) {
            w[0][d] = wL[(d * WKI + r0) * 4 + (o - o_lo)];
            w[1][d] = wL[(d * WKI + r0 + 1) * 4 + (o - o_lo)];
        }

#pragma unroll 2
        for (int nn = 0; nn < 32; ++nn) {
            float4 e0 = *reinterpret_cast<const float4*>(&sE[nn][0]);
            float4 e1 = *reinterpret_cast<const float4*>(&sE[nn][4]);
            float4 e2 = *reinterpret_cast<const float4*>(&sE[nn][8]);
            float4 e3 = *reinterpret_cast<const float4*>(&sE[nn][12]);
            float en[EMB] = {e0.x,e0.y,e0.z,e0.w, e1.x,e1.y,e1.z,e1.w,
                             e2.x,e2.y,e2.z,e2.w, e3.x,e3.y,e3.z,e3.w};
            float a0 = 0.f, a1 = 0.f;
#pragma unroll
            for (int d = 0; d < EMB; ++d) {
                a0 += en[d] * w[0][d];
                a1 += en[d] * w[1][d];
            }
            unsigned int pk = (unsigned int)bfbits(a0) | ((unsigned int)bfbits(a1) << 16);
            __builtin_nontemporal_store(pk,
                reinterpret_cast<unsigned int*>(Wt + (size_t)(n0 + nn) * 12288 + oki0));
        }
    }
}

// ---------------------------------------------------------------------------
// C(4096x2048) = A @ Bt^T; MODE 1 only now: writes GT node-major, scale 2.
// ---------------------------------------------------------------------------
template<int MODE>
__global__ __launch_bounds__(256) void gemm_bt(
    const bf16_t* __restrict__ A, const bf16_t* __restrict__ Bt,
    bf16_t* __restrict__ Cj, bf16_t* __restrict__ GT) {
    __shared__ bf16_t smem[128 * 136];    // 34.8 KB; union of {As,Bs} and T
    bf16_t* As = smem;
    bf16_t* Bs = smem + 4096;
    bf16_t* T  = smem;
    const int tid  = threadIdx.x;
    const int wave = tid >> 6, lane = tid & 63;
    const int pBlk = blockIdx.x * 128;    // node cols
    const int mBlk = blockIdx.y * 128;    // j rows
    const int K = NN;

    const bf16_t* aSrc = A  + (size_t)(mBlk + wave * 32 + (lane >> 2)) * K + (lane & 3) * 8;
    const bf16_t* bSrc = Bt + (size_t)(pBlk + wave * 32 + (lane >> 2)) * K + (lane & 3) * 8;
    bf16_t* aDst = As + wave * 1024;
    bf16_t* bDst = Bs + wave * 1024;

    f32x4 acc[4][4] = {};
    const int wr = wave >> 1, wc = wave & 1;
    const int lrow = lane & 15, lk = (lane >> 4) * 8;

    for (int k0 = 0; k0 < K; k0 += 32) {
        GLOAD16(aSrc + k0,                  aDst);
        GLOAD16(aSrc + k0 + (size_t)16 * K, aDst + 512);
        GLOAD16(bSrc + k0,                  bDst);
        GLOAD16(bSrc + k0 + (size_t)16 * K, bDst + 512);
        __syncthreads();

        bf16x8 af[4], bb[4];
#pragma unroll
        for (int mf = 0; mf < 4; ++mf)
            af[mf] = *reinterpret_cast<const bf16x8*>(
                &As[(wr * 64 + mf * 16 + lrow) * 32 + lk]);
#pragma unroll
        for (int nf = 0; nf < 4; ++nf)
            bb[nf] = *reinterpret_cast<const bf16x8*>(
                &Bs[(wc * 64 + nf * 16 + lrow) * 32 + lk]);
#pragma unroll
        for (int mf = 0; mf < 4; ++mf)
#pragma unroll
            for (int nf = 0; nf < 4; ++nf)
                acc[mf][nf] = __builtin_amdgcn_mfma_f32_16x16x32_bf16(
                    af[mf], bb[nf], acc[mf][nf], 0, 0, 0);
        __syncthreads();
    }

    const int orow = (lane >> 4) * 4, ocol = lane & 15;
    if (MODE == 0) {
#pragma unroll
        for (int mf = 0; mf < 4; ++mf)
#pragma unroll
            for (int nf = 0; nf < 4; ++nf)
#pragma unroll
                for (int r = 0; r < 4; ++r) {
                    size_t row = (size_t)(mBlk + wr * 64 + mf * 16 + orow + r);
                    size_t col = (size_t)(pBlk + wc * 64 + nf * 16 + ocol);
                    Cj[row * NN + col] = (bf16_t)acc[mf][nf][r];
                }
    }
    const float scale = (MODE == 1) ? 2.f : 1.f;
#pragma unroll
    for (int mf = 0; mf < 4; ++mf)
#pragma unroll
        for (int nf = 0; nf < 4; ++nf)
#pragma unroll
            for (int r = 0; r < 4; ++r) {
                int trow = wr * 64 + mf * 16 + orow + r;   // local j
                int tcol = wc * 64 + nf * 16 + ocol;       // local n
                T[(size_t)tcol * 136 + trow] = (bf16_t)(scale * acc[mf][nf][r]);
            }
    __syncthreads();
    {
        const int row = tid >> 1, half = tid & 1;
        const bf16_t* src = T + (size_t)row * 136 + half * 64;
        bf16_t* dst = GT + (size_t)(pBlk + row) * JDIM + mBlk + half * 64;
#pragma unroll
        for (int s = 0; s < 8; ++s)
            *reinterpret_cast<uint4*>(dst + s * 8) =
                *reinterpret_cast<const uint4*>(src + s * 8);
    }
}

// ---------------------------------------------------------------------------
// Final grouped matmul, MFMA. One node per block (grid NN).
// Wt loads now PLAIN (NT caused half-line refetch: lane-quad reads 64B of a
// 128B line; L2 allocate lets ks/ks+1 halves share the fetch). out stays NT.
// ---------------------------------------------------------------------------
__global__ __launch_bounds__(256) void gconv_kernel(
    const float* __restrict__ x,   const float* __restrict__ E,
    const float* __restrict__ bp,  const bf16_t* __restrict__ G1T,
    const bf16_t* __restrict__ G2T, const bf16_t* __restrict__ Wt,
    float* __restrict__ out) {
    __shared__ bf16_t g[64][200];          // 25.6 KB
    const int n = blockIdx.x;
    const int tid = threadIdx.x, wave = tid >> 6, lane = tid & 63;
    const int lrow = lane & 15, lk = (lane >> 4) * 8;
    const int o = wave * 16 + lrow;        // this lane's output col

    // ---- prefetch Wt fragments + bias (independent of LDS) ----
    const bf16_t* wtn = Wt + (size_t)n * 12288 + (size_t)o * WKI;
    bf16x8 bb[6];
#pragma unroll
    for (int ks = 0; ks < 6; ++ks)
        bb[ks] = *reinterpret_cast<const bf16x8*>(wtn + ks * 32 + lk);
    float bo = 0.f;
    {
        const float* en = E + (size_t)n * EMB;
#pragma unroll
        for (int d = 0; d < EMB; ++d) bo += en[d] * bp[d * COUT + o];
    }

    // ---- stage g (cooperative) ----
#pragma unroll
    for (int p = 0; p < 2; ++p) {
        int idx = p * 256 + tid;                 // 0..511
        int b = idx >> 3, ic = (idx & 7) * 8;
        const float4* xs = reinterpret_cast<const float4*>(
            x + ((size_t)b * NN + n) * CIN + ic);
        float4 x0 = xs[0], x1 = xs[1];
        uint4 g1v = *reinterpret_cast<const uint4*>(G1T + (size_t)n * JDIM + idx * 8);
        uint4 g2v = *reinterpret_cast<const uint4*>(G2T + (size_t)n * JDIM + idx * 8);
        float xv[8] = {x0.x, x0.y, x0.z, x0.w, x1.x, x1.y, x1.z, x1.w};
        const bf16_t* g2p = reinterpret_cast<const bf16_t*>(&g2v);
        ushort4 g0b[2], g2b[2];
#pragma unroll
        for (int e = 0; e < 8; ++e) {
            ((unsigned short*)g0b)[e] = bfbits(xv[e]);
            ((unsigned short*)g2b)[e] = bfbits((float)g2p[e] - xv[e]);
        }
        *reinterpret_cast<uint4*>(&g[b][ic])       = *reinterpret_cast<uint4*>(g0b);
        *reinterpret_cast<uint4*>(&g[b][64 + ic])  = g1v;
        *reinterpret_cast<uint4*>(&g[b][128 + ic]) = *reinterpret_cast<uint4*>(g2b);
    }
    __syncthreads();

    // ---- compute: 64x16 output slice per wave, K=192 ----
    f32x4 acc[4] = {};
#pragma unroll
    for (int ks = 0; ks < 6; ++ks)
#pragma unroll
        for (int mf = 0; mf < 4; ++mf) {
            bf16x8 af = *reinterpret_cast<const bf16x8*>(&g[mf * 16 + lrow][ks * 32 + lk]);
            acc[mf] = __builtin_amdgcn_mfma_f32_16x16x32_bf16(af, bb[ks], acc[mf], 0, 0, 0);
        }
#pragma unroll
    for (int mf = 0; mf < 4; ++mf)
#pragma unroll
        for (int r = 0; r < 4; ++r) {
            int b = mf * 16 + (lane >> 4) * 4 + r;
            __builtin_nontemporal_store(acc[mf][r] + bo,
                &out[((size_t)b * NN + n) * COUT + o]);
        }
}

// ---------------------------------------------------------------------------
extern "C" void kernel_launch(void* const* d_in, const int* in_sizes, int n_in,
                              void* d_out, int out_size, void* d_ws, size_t ws_size,
                              hipStream_t stream) {
    const float* x  = (const float*)d_in[0];   // (64,2048,64)
    const float* E  = (const float*)d_in[1];   // (2048,16)
    const float* wp = (const float*)d_in[2];   // (16,3,64,64)
    const float* bp = (const float*)d_in[3];   // (16,64)
    float* out = (float*)d_out;

    bf16_t* ws = (bf16_t*)d_ws;
    bf16_t* Wt  = ws;                          // 2048*12288      = 48 MB
    bf16_t* Sb  = Wt + (size_t)NN * 12288;     // 2048*2048       =  8 MB
    bf16_t* Y0  = Sb + (size_t)NN * NN;        // 4096*2048       = 16 MB
    bf16_t* Y1  = Y0 + (size_t)JDIM * NN;      // 16 MB
    bf16_t* G1T = Y1 + (size_t)JDIM * NN;      // 16 MB  (total 104 MB)
    bf16_t* G2T = Y0;                          // alias: Y0 dead after gemm0

    sy_kernel<<<4096, 256, 0, stream>>>(x, E, Y0, Sb);

    // gemm<0> (512 blocks) + wgen (1536 blocks) fused heterogeneous grid
    gemm0_wgen_kernel<<<2048, 256, 0, stream>>>(Y0, Sb, Y1, G1T, E, wp, Wt);

    dim3 ggrid(NN / 128, JDIM / 128);          // 16 x 32 = 512 blocks
    gemm_bt<1><<<ggrid, 256, 0, stream>>>(Y1, Sb, nullptr, G2T);

    gconv_kernel<<<NN, 256, 0, stream>>>(x, E, bp, G1T, G2T, Wt, out);
}

// Round 9
// 252.096 us; speedup vs baseline: 1.1219x; 1.0073x over previous
//
#include <hip/hip_runtime.h>
#include <math.h>

// AVWGCN: B=64, N=2048, C_IN=C_OUT=64, CHEB_K=3, EMBED=16
#define NN    2048
#define BATCH 64
#define CIN   64
#define COUT  64
#define EMB   16
#define JDIM  4096   // BATCH*CIN
#define WKI   192    // CHEB_K*CIN
#define TPAD  138    // epilogue transpose stride: 276B = 69 dwords (odd) -> conflict-free

typedef __bf16 bf16_t;
typedef __bf16 bf16x8 __attribute__((ext_vector_type(8)));
typedef float  f32x4  __attribute__((ext_vector_type(4)));

#define GLOAD16(gp, lp) __builtin_amdgcn_global_load_lds( \
    (const __attribute__((address_space(1))) void*)(gp),  \
    (__attribute__((address_space(3))) void*)(lp), 16, 0, 0)

static __device__ __forceinline__ unsigned short bfbits(float f) {
    return __builtin_bit_cast(unsigned short, (bf16_t)f);
}

// ---------------------------------------------------------------------------
// Fused support + y0: [0,2048) support rows | [2048,4096) y0 tiles.
// ---------------------------------------------------------------------------
__global__ __launch_bounds__(256) void sy_kernel(
    const float* __restrict__ x, const float* __restrict__ E,
    bf16_t* __restrict__ Y0, bf16_t* __restrict__ Sb) {
    __shared__ float smem[64 * 65];
    const int bid = blockIdx.x;
    const int tid = threadIdx.x;

    if (bid < 2048) {
        // ============ support: Sb[n,:] = softmax(relu(E[n]@E^T)) ===========
        float* vals = smem;
        float* red  = smem + 2048;
        const int n = bid;

        float en[EMB];
#pragma unroll
        for (int d = 0; d < EMB; ++d) en[d] = E[n * EMB + d];

        float lmax = -1e30f;
        for (int m = tid; m < NN; m += 256) {
            const float4* em = reinterpret_cast<const float4*>(E + m * EMB);
            float dot = 0.f;
#pragma unroll
            for (int q = 0; q < EMB / 4; ++q) {
                float4 v = em[q];
                dot += en[q*4+0]*v.x + en[q*4+1]*v.y + en[q*4+2]*v.z + en[q*4+3]*v.w;
            }
            float r = fmaxf(dot, 0.f);
            vals[m] = r;
            lmax = fmaxf(lmax, r);
        }
#pragma unroll
        for (int off = 32; off > 0; off >>= 1)
            lmax = fmaxf(lmax, __shfl_down(lmax, off, 64));
        if ((tid & 63) == 0) red[tid >> 6] = lmax;
        __syncthreads();
        const float gmax = fmaxf(fmaxf(red[0], red[1]), fmaxf(red[2], red[3]));
        __syncthreads();

        float lsum = 0.f;
        for (int m = tid; m < NN; m += 256) {
            float e = expf(vals[m] - gmax);
            vals[m] = e;
            lsum += e;
        }
#pragma unroll
        for (int off = 32; off > 0; off >>= 1)
            lsum += __shfl_down(lsum, off, 64);
        if ((tid & 63) == 0) red[tid >> 6] = lsum;
        __syncthreads();
        const float inv = 1.f / (red[0] + red[1] + red[2] + red[3]);

        for (int m = tid; m < NN; m += 256)
            Sb[(size_t)n * NN + m] = (bf16_t)(vals[m] * inv);
    } else {
        // ============ y0: Y0[b*64+c][n] = x[b][n][c] =======================
        float (*tile)[65] = reinterpret_cast<float(*)[65]>(smem);
        const int yb = bid - 2048;
        const int n0 = (yb & 31) * 64, b = yb >> 5;
        const int c = tid & 63, nn0 = tid >> 6;
        const float* src = x + ((size_t)b * NN + n0) * CIN + c;
#pragma unroll
        for (int p = 0; p < 16; ++p) {
            int nn = nn0 + p * 4;
            tile[nn][c] = src[(size_t)nn * CIN];
        }
        __syncthreads();
        const int cc = tid >> 2, q = tid & 3;
        bf16_t* dst = Y0 + (size_t)(b * 64 + cc) * NN + n0 + q * 16;
#pragma unroll
        for (int s4 = 0; s4 < 4; ++s4) {
            ushort4 pk;
            pk.x = bfbits(tile[q * 16 + s4 * 4 + 0][cc]);
            pk.y = bfbits(tile[q * 16 + s4 * 4 + 1][cc]);
            pk.z = bfbits(tile[q * 16 + s4 * 4 + 2][cc]);
            pk.w = bfbits(tile[q * 16 + s4 * 4 + 3][cc]);
            *reinterpret_cast<ushort4*>(dst + s4 * 4) = pk;
        }
    }
}

// ---------------------------------------------------------------------------
// HETEROGENEOUS kernel: blocks [0,512) = gemm<0> tiles; [512,2048) = wgen.
// r9 changes: (1) wgen stages the fp32 wp window in TWO halves (24.6 KB LDS
// instead of 49.2 -> union 35.4 KB -> 4 blocks/CU, math bit-identical);
// (2) epilogue transpose stride 136 -> 138 (8-way bank conflict -> free).
// ---------------------------------------------------------------------------
__global__ __launch_bounds__(256) void gemm0_wgen_kernel(
    const bf16_t* __restrict__ A, const bf16_t* __restrict__ Bt,
    bf16_t* __restrict__ Cj, bf16_t* __restrict__ GT,
    const float* __restrict__ E, const float* __restrict__ wp,
    bf16_t* __restrict__ Wt) {
    __shared__ float smemF[8848];          // 35.4 KB union
    const int bid = blockIdx.x;
    const int tid = threadIdx.x;

    if (bid < 512) {
        // =================== gemm<0> path (MODE 0) =========================
        bf16_t* As = reinterpret_cast<bf16_t*>(smemF);     // 128*32
        bf16_t* Bs = As + 4096;                            // 128*32
        bf16_t* T  = As;                                   // 128*TPAD epilogue
        const int wave = tid >> 6, lane = tid & 63;
        const int pBlk = (bid & 15) * 128;   // node cols
        const int mBlk = (bid >> 4) * 128;   // j rows
        const int K = NN;

        const bf16_t* aSrc = A  + (size_t)(mBlk + wave * 32 + (lane >> 2)) * K + (lane & 3) * 8;
        const bf16_t* bSrc = Bt + (size_t)(pBlk + wave * 32 + (lane >> 2)) * K + (lane & 3) * 8;
        bf16_t* aDst = As + wave * 1024;
        bf16_t* bDst = Bs + wave * 1024;

        f32x4 acc[4][4] = {};
        const int wr = wave >> 1, wc = wave & 1;
        const int lrow = lane & 15, lk = (lane >> 4) * 8;

        for (int k0 = 0; k0 < K; k0 += 32) {
            GLOAD16(aSrc + k0,                  aDst);
            GLOAD16(aSrc + k0 + (size_t)16 * K, aDst + 512);
            GLOAD16(bSrc + k0,                  bDst);
            GLOAD16(bSrc + k0 + (size_t)16 * K, bDst + 512);
            __syncthreads();

            bf16x8 af[4], bb[4];
#pragma unroll
            for (int mf = 0; mf < 4; ++mf)
                af[mf] = *reinterpret_cast<const bf16x8*>(
                    &As[(wr * 64 + mf * 16 + lrow) * 32 + lk]);
#pragma unroll
            for (int nf = 0; nf < 4; ++nf)
                bb[nf] = *reinterpret_cast<const bf16x8*>(
                    &Bs[(wc * 64 + nf * 16 + lrow) * 32 + lk]);
#pragma unroll
            for (int mf = 0; mf < 4; ++mf)
#pragma unroll
                for (int nf = 0; nf < 4; ++nf)
                    acc[mf][nf] = __builtin_amdgcn_mfma_f32_16x16x32_bf16(
                        af[mf], bb[nf], acc[mf][nf], 0, 0, 0);
            __syncthreads();
        }

        const int orow = (lane >> 4) * 4, ocol = lane & 15;
#pragma unroll
        for (int mf = 0; mf < 4; ++mf)
#pragma unroll
            for (int nf = 0; nf < 4; ++nf)
#pragma unroll
                for (int r = 0; r < 4; ++r) {
                    size_t row = (size_t)(mBlk + wr * 64 + mf * 16 + orow + r);
                    size_t col = (size_t)(pBlk + wc * 64 + nf * 16 + ocol);
                    Cj[row * NN + col] = (bf16_t)acc[mf][nf][r];
                }
#pragma unroll
        for (int mf = 0; mf < 4; ++mf)
#pragma unroll
            for (int nf = 0; nf < 4; ++nf)
#pragma unroll
                for (int r = 0; r < 4; ++r) {
                    int trow = wr * 64 + mf * 16 + orow + r;   // local j
                    int tcol = wc * 64 + nf * 16 + ocol;       // local n
                    T[(size_t)tcol * TPAD + trow] = (bf16_t)acc[mf][nf][r];
                }
        __syncthreads();
        {
            const int row = tid >> 1, half = tid & 1;
            const bf16_t* src = T + (size_t)row * TPAD + half * 64;
            bf16_t* dst = GT + (size_t)(pBlk + row) * JDIM + mBlk + half * 64;
#pragma unroll
            for (int s = 0; s < 8; ++s)
                *reinterpret_cast<uint4*>(dst + s * 8) =
                    *reinterpret_cast<const uint4*>(src + s * 8);
        }
    } else {
        // =========== wgen v5: two-phase fp32 wp staging (24.6 KB) ==========
        float* wL = smemF;                                     // 1536*4 floats
        float (*sE)[16] = reinterpret_cast<float(*)[16]>(smemF + 6144);
        const int wb = bid - 512;
        const int s  = wb % 24;                // oki slice (512 wide)
        const int n0 = (wb / 24) * 32;         // node chunk
        const int oki0 = s * 512 + 2 * tid;
        const int o = oki0 / WKI, r0 = oki0 % WKI;
        const int o_lo = (s * 512) / WKI;
        const int oo_sel = o - o_lo;
        const int col = min(o_lo + (tid & 3), 63);

        if (tid < 128) {
            const int node = tid >> 2, q = tid & 3;
            *reinterpret_cast<float4*>(&sE[node][q * 4]) =
                *reinterpret_cast<const float4*>(E + (size_t)(n0 + node) * EMB + q * 4);
        }

        float w[2][EMB];
#pragma unroll
        for (int ph = 0; ph < 2; ++ph) {
            // stage d in [ph*8, ph*8+8): dr_local = dh*192 + r, 1536 rows
            {
                const int oo = tid & 3;
#pragma unroll
                for (int i = 0; i < 24; ++i) {
                    int drl = (tid >> 2) + i * 64;            // 0..1535
                    wL[drl * 4 + oo] = wp[(size_t)(ph * 1536 + drl) * 64 + col];
                }
            }
            __syncthreads();
#pragma unroll
            for (int dh = 0; dh < 8; ++dh) {
                w[0][ph * 8 + dh] = wL[(dh * WKI + r0) * 4 + oo_sel];
                w[1][ph * 8 + dh] = wL[(dh * WKI + r0 + 1) * 4 + oo_sel];
            }
            __syncthreads();   // protect wL before phase-2 overwrite
        }

#pragma unroll 2
        for (int nn = 0; nn < 32; ++nn) {
            float4 e0 = *reinterpret_cast<const float4*>(&sE[nn][0]);
            float4 e1 = *reinterpret_cast<const float4*>(&sE[nn][4]);
            float4 e2 = *reinterpret_cast<const float4*>(&sE[nn][8]);
            float4 e3 = *reinterpret_cast<const float4*>(&sE[nn][12]);
            float en[EMB] = {e0.x,e0.y,e0.z,e0.w, e1.x,e1.y,e1.z,e1.w,
                             e2.x,e2.y,e2.z,e2.w, e3.x,e3.y,e3.z,e3.w};
            float a0 = 0.f, a1 = 0.f;
#pragma unroll
            for (int d = 0; d < EMB; ++d) {
                a0 += en[d] * w[0][d];
                a1 += en[d] * w[1][d];
            }
            unsigned int pk = (unsigned int)bfbits(a0) | ((unsigned int)bfbits(a1) << 16);
            __builtin_nontemporal_store(pk,
                reinterpret_cast<unsigned int*>(Wt + (size_t)(n0 + nn) * 12288 + oki0));
        }
    }
}

// ---------------------------------------------------------------------------
// C(4096x2048) = A @ Bt^T; MODE 1: writes GT node-major, scale 2.
// ---------------------------------------------------------------------------
template<int MODE>
__global__ __launch_bounds__(256) void gemm_bt(
    const bf16_t* __restrict__ A, const bf16_t* __restrict__ Bt,
    bf16_t* __restrict__ Cj, bf16_t* __restrict__ GT) {
    __shared__ bf16_t smem[128 * TPAD];   // 35.3 KB; union of {As,Bs} and T
    bf16_t* As = smem;
    bf16_t* Bs = smem + 4096;
    bf16_t* T  = smem;
    const int tid  = threadIdx.x;
    const int wave = tid >> 6, lane = tid & 63;
    const int pBlk = blockIdx.x * 128;    // node cols
    const int mBlk = blockIdx.y * 128;    // j rows
    const int K = NN;

    const bf16_t* aSrc = A  + (size_t)(mBlk + wave * 32 + (lane >> 2)) * K + (lane & 3) * 8;
    const bf16_t* bSrc = Bt + (size_t)(pBlk + wave * 32 + (lane >> 2)) * K + (lane & 3) * 8;
    bf16_t* aDst = As + wave * 1024;
    bf16_t* bDst = Bs + wave * 1024;

    f32x4 acc[4][4] = {};
    const int wr = wave >> 1, wc = wave & 1;
    const int lrow = lane & 15, lk = (lane >> 4) * 8;

    for (int k0 = 0; k0 < K; k0 += 32) {
        GLOAD16(aSrc + k0,                  aDst);
        GLOAD16(aSrc + k0 + (size_t)16 * K, aDst + 512);
        GLOAD16(bSrc + k0,                  bDst);
        GLOAD16(bSrc + k0 + (size_t)16 * K, bDst + 512);
        __syncthreads();

        bf16x8 af[4], bb[4];
#pragma unroll
        for (int mf = 0; mf < 4; ++mf)
            af[mf] = *reinterpret_cast<const bf16x8*>(
                &As[(wr * 64 + mf * 16 + lrow) * 32 + lk]);
#pragma unroll
        for (int nf = 0; nf < 4; ++nf)
            bb[nf] = *reinterpret_cast<const bf16x8*>(
                &Bs[(wc * 64 + nf * 16 + lrow) * 32 + lk]);
#pragma unroll
        for (int mf = 0; mf < 4; ++mf)
#pragma unroll
            for (int nf = 0; nf < 4; ++nf)
                acc[mf][nf] = __builtin_amdgcn_mfma_f32_16x16x32_bf16(
                    af[mf], bb[nf], acc[mf][nf], 0, 0, 0);
        __syncthreads();
    }

    const int orow = (lane >> 4) * 4, ocol = lane & 15;
    if (MODE == 0) {
#pragma unroll
        for (int mf = 0; mf < 4; ++mf)
#pragma unroll
            for (int nf = 0; nf < 4; ++nf)
#pragma unroll
                for (int r = 0; r < 4; ++r) {
                    size_t row = (size_t)(mBlk + wr * 64 + mf * 16 + orow + r);
                    size_t col = (size_t)(pBlk + wc * 64 + nf * 16 + ocol);
                    Cj[row * NN + col] = (bf16_t)acc[mf][nf][r];
                }
    }
    const float scale = (MODE == 1) ? 2.f : 1.f;
#pragma unroll
    for (int mf = 0; mf < 4; ++mf)
#pragma unroll
        for (int nf = 0; nf < 4; ++nf)
#pragma unroll
            for (int r = 0; r < 4; ++r) {
                int trow = wr * 64 + mf * 16 + orow + r;   // local j
                int tcol = wc * 64 + nf * 16 + ocol;       // local n
                T[(size_t)tcol * TPAD + trow] = (bf16_t)(scale * acc[mf][nf][r]);
            }
    __syncthreads();
    {
        const int row = tid >> 1, half = tid & 1;
        const bf16_t* src = T + (size_t)row * TPAD + half * 64;
        bf16_t* dst = GT + (size_t)(pBlk + row) * JDIM + mBlk + half * 64;
#pragma unroll
        for (int s = 0; s < 8; ++s)
            *reinterpret_cast<uint4*>(dst + s * 8) =
                *reinterpret_cast<const uint4*>(src + s * 8);
    }
}

// ---------------------------------------------------------------------------
// Final grouped matmul, MFMA. One node per block (grid NN).
// Wt loads plain (L2 glues half-lines); out stores NT.
// ---------------------------------------------------------------------------
__global__ __launch_bounds__(256) void gconv_kernel(
    const float* __restrict__ x,   const float* __restrict__ E,
    const float* __restrict__ bp,  const bf16_t* __restrict__ G1T,
    const bf16_t* __restrict__ G2T, const bf16_t* __restrict__ Wt,
    float* __restrict__ out) {
    __shared__ bf16_t g[64][200];          // 25.6 KB
    const int n = blockIdx.x;
    const int tid = threadIdx.x, wave = tid >> 6, lane = tid & 63;
    const int lrow = lane & 15, lk = (lane >> 4) * 8;
    const int o = wave * 16 + lrow;        // this lane's output col

    // ---- prefetch Wt fragments + bias (independent of LDS) ----
    const bf16_t* wtn = Wt + (size_t)n * 12288 + (size_t)o * WKI;
    bf16x8 bb[6];
#pragma unroll
    for (int ks = 0; ks < 6; ++ks)
        bb[ks] = *reinterpret_cast<const bf16x8*>(wtn + ks * 32 + lk);
    float bo = 0.f;
    {
        const float* en = E + (size_t)n * EMB;
#pragma unroll
        for (int d = 0; d < EMB; ++d) bo += en[d] * bp[d * COUT + o];
    }

    // ---- stage g (cooperative) ----
#pragma unroll
    for (int p = 0; p < 2; ++p) {
        int idx = p * 256 + tid;                 // 0..511
        int b = idx >> 3, ic = (idx & 7) * 8;
        const float4* xs = reinterpret_cast<const float4*>(
            x + ((size_t)b * NN + n) * CIN + ic);
        float4 x0 = xs[0], x1 = xs[1];
        uint4 g1v = *reinterpret_cast<const uint4*>(G1T + (size_t)n * JDIM + idx * 8);
        uint4 g2v = *reinterpret_cast<const uint4*>(G2T + (size_t)n * JDIM + idx * 8);
        float xv[8] = {x0.x, x0.y, x0.z, x0.w, x1.x, x1.y, x1.z, x1.w};
        const bf16_t* g2p = reinterpret_cast<const bf16_t*>(&g2v);
        ushort4 g0b[2], g2b[2];
#pragma unroll
        for (int e = 0; e < 8; ++e) {
            ((unsigned short*)g0b)[e] = bfbits(xv[e]);
            ((unsigned short*)g2b)[e] = bfbits((float)g2p[e] - xv[e]);
        }
        *reinterpret_cast<uint4*>(&g[b][ic])       = *reinterpret_cast<uint4*>(g0b);
        *reinterpret_cast<uint4*>(&g[b][64 + ic])  = g1v;
        *reinterpret_cast<uint4*>(&g[b][128 + ic]) = *reinterpret_cast<uint4*>(g2b);
    }
    __syncthreads();

    // ---- compute: 64x16 output slice per wave, K=192 ----
    f32x4 acc[4] = {};
#pragma unroll
    for (int ks = 0; ks < 6; ++ks)
#pragma unroll
        for (int mf = 0; mf < 4; ++mf) {
            bf16x8 af = *reinterpret_cast<const bf16x8*>(&g[mf * 16 + lrow][ks * 32 + lk]);
            acc[mf] = __builtin_amdgcn_mfma_f32_16x16x32_bf16(af, bb[ks], acc[mf], 0, 0, 0);
        }
#pragma unroll
    for (int mf = 0; mf < 4; ++mf)
#pragma unroll
        for (int r = 0; r < 4; ++r) {
            int b = mf * 16 + (lane >> 4) * 4 + r;
            __builtin_nontemporal_store(acc[mf][r] + bo,
                &out[((size_t)b * NN + n) * COUT + o]);
        }
}

// ---------------------------------------------------------------------------
extern "C" void kernel_launch(void* const* d_in, const int* in_sizes, int n_in,
                              void* d_out, int out_size, void* d_ws, size_t ws_size,
                              hipStream_t stream) {
    const float* x  = (const float*)d_in[0];   // (64,2048,64)
    const float* E  = (const float*)d_in[1];   // (2048,16)
    const float* wp = (const float*)d_in[2];   // (16,3,64,64)
    const float* bp = (const float*)d_in[3];   // (16,64)
    float* out = (float*)d_out;

    bf16_t* ws = (bf16_t*)d_ws;
    bf16_t* Wt  = ws;                          // 2048*12288      = 48 MB
    bf16_t* Sb  = Wt + (size_t)NN * 12288;     // 2048*2048       =  8 MB
    bf16_t* Y0  = Sb + (size_t)NN * NN;        // 4096*2048       = 16 MB
    bf16_t* Y1  = Y0 + (size_t)JDIM * NN;      // 16 MB
    bf16_t* G1T = Y1 + (size_t)JDIM * NN;      // 16 MB  (total 104 MB)
    bf16_t* G2T = Y0;                          // alias: Y0 dead after gemm0

    sy_kernel<<<4096, 256, 0, stream>>>(x, E, Y0, Sb);

    // gemm<0> (512 blocks) + wgen (1536 blocks) fused heterogeneous grid
    gemm0_wgen_kernel<<<2048, 256, 0, stream>>>(Y0, Sb, Y1, G1T, E, wp, Wt);

    dim3 ggrid(NN / 128, JDIM / 128);          // 16 x 32 = 512 blocks
    gemm_bt<1><<<ggrid, 256, 0, stream>>>(Y1, Sb, nullptr, G2T);

    gconv_kernel<<<NN, 256, 0, stream>>>(x, E, bp, G1T, G2T, Wt, out);
}